// Round 3
// baseline (21779.587 us; speedup 1.0000x reference)
//
#include <hip/hip_runtime.h>
#include <hip/hip_bf16.h>

#pragma clang fp contract(off)

#define DEVI __device__ __forceinline__

constexpr int Bc = 8, Cc = 2048, Vc = 512, Hc = 256;

constexpr int W_N = 23;
constexpr int W_OFF[W_N] = {
  0,        524288,  655360,  655872,  656384,  656896,  787968,  788224,
  984832,   985600,  1051136, 1051392, 1116928, 1117184, 1117440, 1117444,
  1182980,  1183236, 1183748, 1183752, 1249288, 1249544, 1249800 };
constexpr int W_SZ[W_N] = {
  524288, 131072, 512, 512, 512, 131072, 256, 196608, 768,
  65536, 256, 65536, 256, 256, 1, 65536, 256, 512, 2, 65536, 256, 256, 1 };
constexpr int W_TOT = 1249804;
// slots: 0 lit_emb 1 ce_w1 2 ce_b1 3 ce_g 4 ce_beta 5 ce_w2 6 ce_b2
// 7 attn_in_w 8 attn_in_b 9 attn_out_w 10 attn_out_b 11 vs_w1 12 vs_b1
// 13 vs_w2 14 vs_b2 15 ap_w1 16 ap_b1 17 ap_w2 18 ap_b2 19 sp_w1 20 sp_b1
// 21 sp_w2 22 sp_b2

constexpr size_t BASE_O = 1249808;
constexpr size_t KH_O   = BASE_O + 4194304;
constexpr size_t VH_O   = KH_O   + 4194304;
constexpr size_t QH_O   = VH_O   + 4194304;
constexpr size_t OO_O   = QH_O   + 1048576;
constexpr size_t VS_O   = OO_O   + 1048576;
constexpr size_t SC_O   = VS_O   + 1048576;
constexpr size_t FTOT   = SC_O   + 4096;   // ~65 MB + int area

struct SrcPtrs { const void* p[W_N]; };

DEVI float gelu_ref(float x) {
  // jax.nn.gelu(approximate=False): x * (erf(x / sqrt(2)) + 1) / 2
  return (x * (erff(x / 1.41421356237309504880f) + 1.0f)) * 0.5f;
}

// ---------------- dtype probe ----------------
__global__ __launch_bounds__(256) void k_detect(const unsigned short* __restrict__ lit,
                                                int* __restrict__ dflag) {
  __shared__ int red[256];
  int t = threadIdx.x, c = 0;
  for (int i = t; i < 4096; i += 256) {
    unsigned e = (lit[i] >> 7) & 0xFF;
    if (e >= 0x8F) c++;
  }
  red[t] = c;
  __syncthreads();
  for (int s = 128; s > 0; s >>= 1) {
    if (t < s) red[t] += red[t + s];
    __syncthreads();
  }
  if (t == 0) dflag[0] = (red[0] > 64) ? 1 : 0;
}

__global__ __launch_bounds__(256) void k_convert(SrcPtrs sp, float* __restrict__ wf,
                                                 const int* __restrict__ dflag) {
  int idx = blockIdx.x * 256 + threadIdx.x;
  if (idx >= W_TOT) return;
  const int isf32 = dflag[0];
  int i = 0;
  while (i + 1 < W_N && idx >= W_OFF[i + 1]) i++;
  int j = idx - W_OFF[i];
  float v = 0.f;
  if (j < W_SZ[i]) {
    if (isf32) v = ((const float*)sp.p[i])[j];
    else {
      unsigned int u = (unsigned int)((const unsigned short*)sp.p[i])[j] << 16;
      v = __uint_as_float(u);
    }
  }
  wf[idx] = v;
}

__global__ __launch_bounds__(256) void k_init(float* __restrict__ vsarr,
    int* __restrict__ assign, int* __restrict__ flags) {
  int idx = blockIdx.x * 256 + threadIdx.x;
  vsarr[idx] = 0.f;
  if (idx < 4096) assign[idx] = 2;
  if (idx < 3) flags[idx] = 0;
}

// ---------------- clause embedding (once) ----------------
__global__ __launch_bounds__(256) void k_base(const int* __restrict__ formula,
    const float* __restrict__ wf, float* __restrict__ base) {
  __shared__ float xs[16][256];
  __shared__ float h1[16][512];
  __shared__ float mv[16], vr[16];
  const int t = threadIdx.x;
  const int n0 = blockIdx.x * 16;
  const float* lit = wf + W_OFF[0];
  for (int r = 0; r < 16; ++r) {
    int n = n0 + r;
    int f0 = formula[n*3+0], f1 = formula[n*3+1], f2 = formula[n*3+2];
    xs[r][t] = (lit[f0*256 + t] + lit[f1*256 + t] + lit[f2*256 + t]) / 3.0f;
  }
  __syncthreads();
  {
    const float* w0 = wf + W_OFF[1] + (size_t)t * 256;
    const float* w1 = wf + W_OFF[1] + (size_t)(t + 256) * 256;
    float a0[16], a1[16];
    #pragma unroll
    for (int r = 0; r < 16; ++r) { a0[r] = 0.f; a1[r] = 0.f; }
    for (int k = 0; k < 256; ++k) {
      float wa = w0[k], wb = w1[k];
      #pragma unroll
      for (int r = 0; r < 16; ++r) {
        a0[r] = fmaf(xs[r][k], wa, a0[r]);
        a1[r] = fmaf(xs[r][k], wb, a1[r]);
      }
    }
    float b0 = wf[W_OFF[2] + t], b1b = wf[W_OFF[2] + t + 256];
    #pragma unroll
    for (int r = 0; r < 16; ++r) {
      h1[r][t] = a0[r] + b0;
      h1[r][t + 256] = a1[r] + b1b;
    }
  }
  __syncthreads();
  if (t < 16) {
    float s = 0.f;
    for (int k = 0; k < 512; ++k) s += h1[t][k];
    float m = s / 512.0f;
    float v = 0.f;
    for (int k = 0; k < 512; ++k) { float d = h1[t][k] - m; float d2 = d * d; v += d2; }
    mv[t] = m; vr[t] = v / 512.0f;
  }
  __syncthreads();
  {
    const float* g  = wf + W_OFF[3];
    const float* be = wf + W_OFF[4];
    for (int r = 0; r < 16; ++r) {
      float sd = sqrtf(vr[r] + 1e-5f);
      for (int c = t; c < 512; c += 256) {
        float val = (h1[r][c] - mv[r]) / sd * g[c] + be[c];
        h1[r][c] = gelu_ref(val);
      }
    }
  }
  __syncthreads();
  {
    const float* w2 = wf + W_OFF[5] + (size_t)t * 512;
    float acc[16];
    #pragma unroll
    for (int r = 0; r < 16; ++r) acc[r] = 0.f;
    for (int k = 0; k < 512; ++k) {
      float wk = w2[k];
      #pragma unroll
      for (int r = 0; r < 16; ++r) acc[r] = fmaf(h1[r][k], wk, acc[r]);
    }
    float b2 = wf[W_OFF[6] + t];
    for (int r = 0; r < 16; ++r)
      base[(size_t)(n0 + r) * 256 + t] = acc[r] + b2;
  }
}

// ---------------- per-iteration ----------------
__global__ __launch_bounds__(256) void k_clause_kv(const int* __restrict__ formula,
    const float* __restrict__ base, const int* __restrict__ assign,
    const float* __restrict__ wf, float* __restrict__ kh, float* __restrict__ vh,
    const int* __restrict__ flags) {
  if (flags[0]) return;
  __shared__ float xs[16][256];
  __shared__ float fac[16];
  const int t = threadIdx.x;
  const int n0 = blockIdx.x * 16;
  const int b = n0 / Cc;
  if (t < 16) {
    int n = n0 + t;
    bool sat = false;
    #pragma unroll
    for (int l = 0; l < 3; ++l) {
      int f = formula[n*3 + l];
      int a = assign[b * Vc + (f >> 1)];
      sat = sat || (a == (f & 1));
    }
    fac[t] = 1.0f - 0.9f * (sat ? 1.f : 0.f);
  }
  __syncthreads();
  for (int r = 0; r < 16; ++r)
    xs[r][t] = base[(size_t)(n0 + r) * 256 + t] * fac[r];
  __syncthreads();
  const float* wk_ = wf + W_OFF[7] + (size_t)(256 + t) * 256;
  const float* wv_ = wf + W_OFF[7] + (size_t)(512 + t) * 256;
  float aK[16], aV[16];
  #pragma unroll
  for (int r = 0; r < 16; ++r) { aK[r] = 0.f; aV[r] = 0.f; }
  for (int k = 0; k < 256; ++k) {
    float wa = wk_[k], wb = wv_[k];
    #pragma unroll
    for (int r = 0; r < 16; ++r) {
      aK[r] = fmaf(xs[r][k], wa, aK[r]);
      aV[r] = fmaf(xs[r][k], wb, aV[r]);
    }
  }
  float bk = wf[W_OFF[8] + 256 + t], bv = wf[W_OFF[8] + 512 + t];
  int head = t >> 5, d = t & 31;
  float* kb = kh + (size_t)(b * 8 + head) * 2048 * 32;
  float* vb = vh + (size_t)(b * 8 + head) * 2048 * 32;
  int c0 = n0 - b * Cc;
  for (int r = 0; r < 16; ++r) {
    kb[(size_t)(c0 + r) * 32 + d] = aK[r] + bk;
    vb[(size_t)(c0 + r) * 32 + d] = aV[r] + bv;
  }
}

__global__ __launch_bounds__(256) void k_q(const float* __restrict__ vsarr,
    const float* __restrict__ wf, float* __restrict__ qh,
    const int* __restrict__ flags) {
  if (flags[0]) return;
  __shared__ float xs[16][256];
  const int t = threadIdx.x;
  const int n0 = blockIdx.x * 16;
  for (int r = 0; r < 16; ++r) xs[r][t] = vsarr[(size_t)(n0 + r) * 256 + t];
  __syncthreads();
  const float* wr = wf + W_OFF[7] + (size_t)t * 256;
  float acc[16];
  #pragma unroll
  for (int r = 0; r < 16; ++r) acc[r] = 0.f;
  for (int k = 0; k < 256; ++k) {
    float wk = wr[k];
    #pragma unroll
    for (int r = 0; r < 16; ++r) acc[r] = fmaf(xs[r][k], wk, acc[r]);
  }
  float bq = wf[W_OFF[8] + t];
  int b = n0 / Vc, vloc = n0 % Vc;
  int head = t >> 5, d = t & 31;
  float* qb = qh + (size_t)(b * 8 + head) * 512 * 32;
  for (int r = 0; r < 16; ++r)
    qb[(size_t)(vloc + r) * 32 + d] = acc[r] + bq;
}

// exact 3-pass softmax attention; one wave per block, lane = q-row
__global__ __launch_bounds__(64) void k_attn(const float* __restrict__ qh,
    const float* __restrict__ kh, const float* __restrict__ vh,
    float* __restrict__ oo, const int* __restrict__ flags) {
  if (flags[0]) return;
  int blk = blockIdx.x;      // 512 = 64 bh * 8 qt
  int qt = blk & 7, bh = blk >> 3;
  int lane = threadIdx.x;
  int q = qt * 64 + lane;
  const float* qp = qh + ((size_t)bh * 512 + q) * 32;
  float qv[32];
  #pragma unroll
  for (int d = 0; d < 32; ++d) qv[d] = qp[d];
  const float* kb = kh + (size_t)bh * 2048 * 32;
  const float* vb = vh + (size_t)bh * 2048 * 32;
  const float SCALE = 5.65685424949238019521f;  // f32(sqrt(32))
  float M = -3.402823466e38f;
  for (int j = 0; j < 2048; ++j) {
    const float* kr = kb + (size_t)j * 32;
    float s = 0.f;
    #pragma unroll
    for (int d = 0; d < 32; ++d) s = fmaf(qv[d], kr[d], s);
    s = s / SCALE;
    M = fmaxf(M, s);
  }
  float L = 0.f;
  for (int j = 0; j < 2048; ++j) {
    const float* kr = kb + (size_t)j * 32;
    float s = 0.f;
    #pragma unroll
    for (int d = 0; d < 32; ++d) s = fmaf(qv[d], kr[d], s);
    s = s / SCALE;
    L += expf(s - M);
  }
  float o[32];
  #pragma unroll
  for (int d = 0; d < 32; ++d) o[d] = 0.f;
  for (int j = 0; j < 2048; ++j) {
    const float* kr = kb + (size_t)j * 32;
    const float* vr2 = vb + (size_t)j * 32;
    float s = 0.f;
    #pragma unroll
    for (int d = 0; d < 32; ++d) s = fmaf(qv[d], kr[d], s);
    s = s / SCALE;
    float w = expf(s - M) / L;   // normalized weight first (softmax then PV)
    #pragma unroll
    for (int d = 0; d < 32; ++d) o[d] = fmaf(w, vr2[d], o[d]);
  }
  int b = bh >> 3, hh = bh & 7;
  float* dst = oo + ((size_t)(b * 512 + q)) * 256 + hh * 32;
  #pragma unroll
  for (int d = 0; d < 32; ++d) dst[d] = o[d];
}

__global__ __launch_bounds__(256) void k_outproj(const float* __restrict__ oo,
    const float* __restrict__ wf, float* __restrict__ vsarr,
    const int* __restrict__ flags) {
  if (flags[0]) return;
  __shared__ float xs[16][256];
  const int t = threadIdx.x;
  const int n0 = blockIdx.x * 16;
  for (int r = 0; r < 16; ++r) xs[r][t] = oo[(size_t)(n0 + r) * 256 + t];
  __syncthreads();
  const float* wr = wf + W_OFF[9] + (size_t)t * 256;
  float acc[16];
  #pragma unroll
  for (int r = 0; r < 16; ++r) acc[r] = 0.f;
  for (int k = 0; k < 256; ++k) {
    float wk = wr[k];
    #pragma unroll
    for (int r = 0; r < 16; ++r) acc[r] = fmaf(xs[r][k], wk, acc[r]);
  }
  float bo = wf[W_OFF[10] + t];
  for (int r = 0; r < 16; ++r)
    vsarr[(size_t)(n0 + r) * 256 + t] = acc[r] + bo;
}

__global__ __launch_bounds__(256) void k_scores(const float* __restrict__ vsarr,
    const float* __restrict__ wf, const int* __restrict__ assign,
    float* __restrict__ sc, const int* __restrict__ flags) {
  if (flags[0]) return;
  __shared__ float xs[16][256];
  __shared__ float h[16][256];
  const int t = threadIdx.x;
  const int n0 = blockIdx.x * 16;
  for (int r = 0; r < 16; ++r) xs[r][t] = vsarr[(size_t)(n0 + r) * 256 + t];
  __syncthreads();
  const float* wr = wf + W_OFF[11] + (size_t)t * 256;
  float acc[16];
  #pragma unroll
  for (int r = 0; r < 16; ++r) acc[r] = 0.f;
  for (int k = 0; k < 256; ++k) {
    float wk = wr[k];
    #pragma unroll
    for (int r = 0; r < 16; ++r) acc[r] = fmaf(xs[r][k], wk, acc[r]);
  }
  float b1 = wf[W_OFF[12] + t];
  for (int r = 0; r < 16; ++r) h[r][t] = gelu_ref(acc[r] + b1);
  __syncthreads();
  if (t < 16) {
    const float* w2 = wf + W_OFF[13];
    float p = 0.f;
    for (int k = 0; k < 256; ++k) p = fmaf(h[t][k], w2[k], p);
    float s = p + wf[W_OFF[14]];
    int n = n0 + t;
    if (assign[n] != 2) s += -1e9f;
    sc[n] = s;
  }
}

__global__ __launch_bounds__(256) void k_select(const float* __restrict__ sc,
    const float* __restrict__ vsarr, const float* __restrict__ wf,
    int* __restrict__ assign, int* __restrict__ selb, int* __restrict__ flags) {
  if (flags[0]) return;
  const int b = blockIdx.x, t = threadIdx.x;
  __shared__ float sv[256];
  __shared__ int   si[256];
  float v0 = sc[b * 512 + t], v1 = sc[b * 512 + 256 + t];
  float bv; int bi;
  if (v1 > v0) { bv = v1; bi = t + 256; } else { bv = v0; bi = t; }
  sv[t] = bv; si[t] = bi;
  __syncthreads();
  for (int s = 128; s > 0; s >>= 1) {
    if (t < s) {
      float ov = sv[t + s]; int oi = si[t + s];
      if (ov > sv[t] || (ov == sv[t] && oi < si[t])) { sv[t] = ov; si[t] = oi; }
    }
    __syncthreads();
  }
  const int sel = si[0];
  __shared__ float x[256];
  __shared__ float h[256];
  x[t] = vsarr[((size_t)(b * 512 + sel)) * 256 + t];
  __syncthreads();
  const float* wr = wf + W_OFF[15] + (size_t)t * 256;
  float a = 0.f;
  for (int k = 0; k < 256; ++k) a = fmaf(x[k], wr[k], a);
  h[t] = gelu_ref(a + wf[W_OFF[16] + t]);
  __syncthreads();
  if (t == 0) {
    const float* w2 = wf + W_OFF[17];
    float l0 = 0.f, l1 = 0.f;
    for (int k = 0; k < 256; ++k) l0 = fmaf(h[k], w2[k], l0);
    for (int k = 0; k < 256; ++k) l1 = fmaf(h[k], w2[256 + k], l1);
    l0 += wf[W_OFF[18]];
    l1 += wf[W_OFF[18] + 1];
    int na = (l1 > l0) ? 1 : 0;
    assign[b * 512 + sel] = na;
    selb[b] = sel;
    if (b == 0) { flags[1] = 0; flags[2] = 0; }
  }
}

__global__ __launch_bounds__(256) void k_conflict(const int* __restrict__ formula,
    const int* __restrict__ assign, int* __restrict__ flags) {
  if (flags[0]) return;
  int idx = blockIdx.x * 256 + threadIdx.x;
  int b = idx >> 11;
  bool sat = false, alla = true;
  #pragma unroll
  for (int l = 0; l < 3; ++l) {
    int f = formula[idx * 3 + l];
    int a = assign[b * 512 + (f >> 1)];
    sat = sat || (a == (f & 1));
    alla = alla && (a != 2);
  }
  bool conf = alla && !sat;
  unsigned long long cb = __ballot(conf);
  int lane = threadIdx.x & 63;
  if (cb && lane == 0) atomicOr(&flags[1], 1);
  if (idx < 4096) {
    unsigned long long ub = __ballot(assign[idx] == 2);
    if (lane == 0 && ub) atomicAdd(&flags[2], (int)__popcll(ub));
  }
}

__global__ __launch_bounds__(64) void k_finalize(int* __restrict__ assign,
    const int* __restrict__ selb, int* __restrict__ flags) {
  if (flags[0]) return;
  int t = threadIdx.x;
  int ac = flags[1], ua = flags[2];
  if (ac && t < 8) assign[t * 512 + selb[t]] = 2;
  if (t == 0 && !ac && ua == 0) flags[0] = 1;
}

__global__ __launch_bounds__(256) void k_issat(const float* __restrict__ vsarr,
    const int* __restrict__ assign, const float* __restrict__ wf,
    void* __restrict__ outv, const int* __restrict__ dflag) {
  const int b = blockIdx.x, t = threadIdx.x;
  const int isf32 = dflag[0];
  __shared__ float x[256];
  __shared__ float h[256];
  float s = 0.f;
  for (int v = 0; v < 512; ++v) s += vsarr[((size_t)(b * 512 + v)) * 256 + t];
  x[t] = s / 512.0f;
  __syncthreads();
  const float* wr = wf + W_OFF[19] + (size_t)t * 256;
  float a = 0.f;
  for (int k = 0; k < 256; ++k) a = fmaf(x[k], wr[k], a);
  h[t] = gelu_ref(a + wf[W_OFF[20] + t]);
  __syncthreads();
  if (t == 0) {
    const float* w2 = wf + W_OFF[21];
    float l = 0.f;
    for (int k = 0; k < 256; ++k) l = fmaf(h[k], w2[k], l);
    l += wf[W_OFF[22]];
    float sig = 1.f / (1.f + expf(-l));
    if (isf32) ((float*)outv)[b] = sig;
    else ((__hip_bfloat16*)outv)[b] = __float2bfloat16(sig);
  }
  for (int i = t; i < 512; i += 256) {
    float av = (float)assign[b * 512 + i];
    if (isf32) ((float*)outv)[8 + b * 512 + i] = av;
    else ((__hip_bfloat16*)outv)[8 + b * 512 + i] = __float2bfloat16(av);
  }
}

extern "C" void kernel_launch(void* const* d_in, const int* in_sizes, int n_in,
                              void* d_out, int out_size, void* d_ws, size_t ws_size,
                              hipStream_t stream) {
  (void)in_sizes; (void)n_in; (void)out_size; (void)ws_size;
  const int* formula = (const int*)d_in[0];
  float* wf = (float*)d_ws;
  SrcPtrs sp;
  for (int i = 0; i < W_N; ++i) sp.p[i] = d_in[i + 1];
  float* base = wf + BASE_O;
  float* kh   = wf + KH_O;
  float* vh   = wf + VH_O;
  float* qh   = wf + QH_O;
  float* oo   = wf + OO_O;
  float* vs   = wf + VS_O;
  float* sc   = wf + SC_O;
  int* iw     = (int*)(wf + FTOT);
  int* assign = iw;
  int* selb   = iw + 4096;
  int* flags  = iw + 4104;
  int* dflag  = iw + 4107;

  k_detect<<<1, 256, 0, stream>>>((const unsigned short*)d_in[1], dflag);
  k_convert<<<(W_TOT + 255) / 256, 256, 0, stream>>>(sp, wf, dflag);
  k_init<<<4096, 256, 0, stream>>>(vs, assign, flags);
  k_base<<<1024, 256, 0, stream>>>(formula, wf, base);
  for (int it = 0; it < 8; ++it) {
    k_clause_kv<<<1024, 256, 0, stream>>>(formula, base, assign, wf, kh, vh, flags);
    k_q<<<256, 256, 0, stream>>>(vs, wf, qh, flags);
    k_attn<<<512, 64, 0, stream>>>(qh, kh, vh, oo, flags);
    k_outproj<<<256, 256, 0, stream>>>(oo, wf, vs, flags);
    k_scores<<<256, 256, 0, stream>>>(vs, wf, assign, sc, flags);
    k_select<<<8, 256, 0, stream>>>(sc, vs, wf, assign, selb, flags);
    k_conflict<<<64, 256, 0, stream>>>(formula, assign, flags);
    k_finalize<<<1, 64, 0, stream>>>(assign, selb, flags);
  }
  k_issat<<<8, 256, 0, stream>>>(vs, assign, wf, d_out, dflag);
}

// Round 4
// 6402.693 us; speedup vs baseline: 3.4016x; 3.4016x over previous
//
#include <hip/hip_runtime.h>
#include <hip/hip_bf16.h>

#pragma clang fp contract(off)

#define DEVI __device__ __forceinline__

constexpr int Bc = 8, Cc = 2048, Vc = 512, Hc = 256;

constexpr int W_N = 23;
constexpr int W_OFF[W_N] = {
  0,        524288,  655360,  655872,  656384,  656896,  787968,  788224,
  984832,   985600,  1051136, 1051392, 1116928, 1117184, 1117440, 1117444,
  1182980,  1183236, 1183748, 1183752, 1249288, 1249544, 1249800 };
constexpr int W_SZ[W_N] = {
  524288, 131072, 512, 512, 512, 131072, 256, 196608, 768,
  65536, 256, 65536, 256, 256, 1, 65536, 256, 512, 2, 65536, 256, 256, 1 };
constexpr int W_TOT = 1249804;
// slots: 0 lit_emb 1 ce_w1 2 ce_b1 3 ce_g 4 ce_beta 5 ce_w2 6 ce_b2
// 7 attn_in_w 8 attn_in_b 9 attn_out_w 10 attn_out_b 11 vs_w1 12 vs_b1
// 13 vs_w2 14 vs_b2 15 ap_w1 16 ap_b1 17 ap_w2 18 ap_b2 19 sp_w1 20 sp_b1
// 21 sp_w2 22 sp_b2

constexpr size_t BASE_O = 1249808;
constexpr size_t KH_O   = BASE_O + 4194304;
constexpr size_t VH_O   = KH_O   + 4194304;
constexpr size_t QH_O   = VH_O   + 4194304;
constexpr size_t OO_O   = QH_O   + 1048576;
constexpr size_t VS_O   = OO_O   + 1048576;
constexpr size_t SC_O   = VS_O   + 1048576;
constexpr size_t FTOT   = SC_O   + 4096;   // ~65 MB + int area

struct SrcPtrs { const void* p[W_N]; };

DEVI float gelu_ref(float x) {
  return (x * (erff(x / 1.41421356237309504880f) + 1.0f)) * 0.5f;
}

// ---------------- dtype probe ----------------
__global__ __launch_bounds__(256) void k_detect(const unsigned short* __restrict__ lit,
                                                int* __restrict__ dflag) {
  __shared__ int red[256];
  int t = threadIdx.x, c = 0;
  for (int i = t; i < 4096; i += 256) {
    unsigned e = (lit[i] >> 7) & 0xFF;
    if (e >= 0x8F) c++;
  }
  red[t] = c;
  __syncthreads();
  for (int s = 128; s > 0; s >>= 1) {
    if (t < s) red[t] += red[t + s];
    __syncthreads();
  }
  if (t == 0) dflag[0] = (red[0] > 64) ? 1 : 0;
}

__global__ __launch_bounds__(256) void k_convert(SrcPtrs sp, float* __restrict__ wf,
                                                 const int* __restrict__ dflag) {
  int idx = blockIdx.x * 256 + threadIdx.x;
  if (idx >= W_TOT) return;
  const int isf32 = dflag[0];
  int i = 0;
  while (i + 1 < W_N && idx >= W_OFF[i + 1]) i++;
  int j = idx - W_OFF[i];
  float v = 0.f;
  if (j < W_SZ[i]) {
    if (isf32) v = ((const float*)sp.p[i])[j];
    else {
      unsigned int u = (unsigned int)((const unsigned short*)sp.p[i])[j] << 16;
      v = __uint_as_float(u);
    }
  }
  wf[idx] = v;
}

__global__ __launch_bounds__(256) void k_init(float* __restrict__ vsarr,
    int* __restrict__ assign, int* __restrict__ flags) {
  int idx = blockIdx.x * 256 + threadIdx.x;
  vsarr[idx] = 0.f;
  if (idx < 4096) assign[idx] = 2;
  if (idx < 3) flags[idx] = 0;
}

// ---------------- clause embedding (once) ----------------
__global__ __launch_bounds__(256) void k_base(const int* __restrict__ formula,
    const float* __restrict__ wf, float* __restrict__ base) {
  __shared__ float xs[16][256];
  __shared__ float h1[16][512];
  __shared__ float mv[16], vr[16];
  const int t = threadIdx.x;
  const int n0 = blockIdx.x * 16;
  const float* lit = wf + W_OFF[0];
  for (int r = 0; r < 16; ++r) {
    int n = n0 + r;
    int f0 = formula[n*3+0], f1 = formula[n*3+1], f2 = formula[n*3+2];
    xs[r][t] = (lit[f0*256 + t] + lit[f1*256 + t] + lit[f2*256 + t]) / 3.0f;
  }
  __syncthreads();
  {
    const float* w0 = wf + W_OFF[1] + (size_t)t * 256;
    const float* w1 = wf + W_OFF[1] + (size_t)(t + 256) * 256;
    float a0[16], a1[16];
    #pragma unroll
    for (int r = 0; r < 16; ++r) { a0[r] = 0.f; a1[r] = 0.f; }
    for (int k = 0; k < 256; ++k) {
      float wa = w0[k], wb = w1[k];
      #pragma unroll
      for (int r = 0; r < 16; ++r) {
        a0[r] = fmaf(xs[r][k], wa, a0[r]);
        a1[r] = fmaf(xs[r][k], wb, a1[r]);
      }
    }
    float b0 = wf[W_OFF[2] + t], b1b = wf[W_OFF[2] + t + 256];
    #pragma unroll
    for (int r = 0; r < 16; ++r) {
      h1[r][t] = a0[r] + b0;
      h1[r][t + 256] = a1[r] + b1b;
    }
  }
  __syncthreads();
  if (t < 16) {
    float s = 0.f;
    for (int k = 0; k < 512; ++k) s += h1[t][k];
    float m = s / 512.0f;
    float v = 0.f;
    for (int k = 0; k < 512; ++k) { float d = h1[t][k] - m; float d2 = d * d; v += d2; }
    mv[t] = m; vr[t] = v / 512.0f;
  }
  __syncthreads();
  {
    const float* g  = wf + W_OFF[3];
    const float* be = wf + W_OFF[4];
    for (int r = 0; r < 16; ++r) {
      float sd = sqrtf(vr[r] + 1e-5f);
      for (int c = t; c < 512; c += 256) {
        float val = (h1[r][c] - mv[r]) / sd * g[c] + be[c];
        h1[r][c] = gelu_ref(val);
      }
    }
  }
  __syncthreads();
  {
    const float* w2 = wf + W_OFF[5] + (size_t)t * 512;
    float acc[16];
    #pragma unroll
    for (int r = 0; r < 16; ++r) acc[r] = 0.f;
    for (int k = 0; k < 512; ++k) {
      float wk = w2[k];
      #pragma unroll
      for (int r = 0; r < 16; ++r) acc[r] = fmaf(h1[r][k], wk, acc[r]);
    }
    float b2 = wf[W_OFF[6] + t];
    for (int r = 0; r < 16; ++r)
      base[(size_t)(n0 + r) * 256 + t] = acc[r] + b2;
  }
}

// ---------------- per-iteration ----------------
__global__ __launch_bounds__(256) void k_clause_kv(const int* __restrict__ formula,
    const float* __restrict__ base, const int* __restrict__ assign,
    const float* __restrict__ wf, float* __restrict__ kh, float* __restrict__ vh,
    const int* __restrict__ flags) {
  if (flags[0]) return;
  __shared__ float xs[16][256];
  __shared__ float fac[16];
  const int t = threadIdx.x;
  const int n0 = blockIdx.x * 16;
  const int b = n0 / Cc;
  if (t < 16) {
    int n = n0 + t;
    bool sat = false;
    #pragma unroll
    for (int l = 0; l < 3; ++l) {
      int f = formula[n*3 + l];
      int a = assign[b * Vc + (f >> 1)];
      sat = sat || (a == (f & 1));
    }
    fac[t] = 1.0f - 0.9f * (sat ? 1.f : 0.f);
  }
  __syncthreads();
  for (int r = 0; r < 16; ++r)
    xs[r][t] = base[(size_t)(n0 + r) * 256 + t] * fac[r];
  __syncthreads();
  const float* wk_ = wf + W_OFF[7] + (size_t)(256 + t) * 256;
  const float* wv_ = wf + W_OFF[7] + (size_t)(512 + t) * 256;
  float aK[16], aV[16];
  #pragma unroll
  for (int r = 0; r < 16; ++r) { aK[r] = 0.f; aV[r] = 0.f; }
  for (int k = 0; k < 256; ++k) {
    float wa = wk_[k], wb = wv_[k];
    #pragma unroll
    for (int r = 0; r < 16; ++r) {
      aK[r] = fmaf(xs[r][k], wa, aK[r]);
      aV[r] = fmaf(xs[r][k], wb, aV[r]);
    }
  }
  float bk = wf[W_OFF[8] + 256 + t], bv = wf[W_OFF[8] + 512 + t];
  int head = t >> 5, d = t & 31;
  float* kb = kh + (size_t)(b * 8 + head) * 2048 * 32;
  float* vb = vh + (size_t)(b * 8 + head) * 2048 * 32;
  int c0 = n0 - b * Cc;
  for (int r = 0; r < 16; ++r) {
    kb[(size_t)(c0 + r) * 32 + d] = aK[r] + bk;
    vb[(size_t)(c0 + r) * 32 + d] = aV[r] + bv;
  }
}

__global__ __launch_bounds__(256) void k_q(const float* __restrict__ vsarr,
    const float* __restrict__ wf, float* __restrict__ qh,
    const int* __restrict__ flags) {
  if (flags[0]) return;
  __shared__ float xs[16][256];
  const int t = threadIdx.x;
  const int n0 = blockIdx.x * 16;
  for (int r = 0; r < 16; ++r) xs[r][t] = vsarr[(size_t)(n0 + r) * 256 + t];
  __syncthreads();
  const float* wr = wf + W_OFF[7] + (size_t)t * 256;
  float acc[16];
  #pragma unroll
  for (int r = 0; r < 16; ++r) acc[r] = 0.f;
  for (int k = 0; k < 256; ++k) {
    float wk = wr[k];
    #pragma unroll
    for (int r = 0; r < 16; ++r) acc[r] = fmaf(xs[r][k], wk, acc[r]);
  }
  float bq = wf[W_OFF[8] + t];
  int b = n0 / Vc, vloc = n0 % Vc;
  int head = t >> 5, d = t & 31;
  float* qb = qh + (size_t)(b * 8 + head) * 512 * 32;
  for (int r = 0; r < 16; ++r)
    qb[(size_t)(vloc + r) * 32 + d] = acc[r] + bq;
}

// ---- tiled exact-softmax attention ----
// block = (bh, 64-q tile); 256 threads = 4 waves; 2-pass (max, then sumexp+PV).
// Per-element s keeps the exact sequential d-order fmaf chain of the passing
// reference kernel; M is order-free max; L and PV are reassociated sums
// (BLAS-class deviation only). Swizzle: bh = blk&63 so one XCD sees 8 bh
// (K+V = 4 MB = its L2).
__global__ __launch_bounds__(256) void k_attn(const float* __restrict__ qh,
    const float* __restrict__ kh, const float* __restrict__ vh,
    float* __restrict__ oo, const int* __restrict__ flags) {
  if (flags[0]) return;
  __shared__ float ks[64 * 32];       // K chunk (64 rows)
  __shared__ float vsd[64 * 32];      // V chunk
  __shared__ float sw[64 * 65];       // exp weights, padded stride 65
  __shared__ float red[4][64];
  const int blk = blockIdx.x;         // 512 = 64 bh * 8 qt
  const int bh = blk & 63, qt = blk >> 6;
  const int t = threadIdx.x;
  const int w = t >> 6, q = t & 63;
  const float SCALE = 5.65685424949238019521f;  // f32(sqrt(32))

  // Q row in registers (each of the 4 waves loads the same 64 rows)
  const float* qp = qh + ((size_t)bh * 512 + qt * 64 + q) * 32;
  float4 qv4[8];
  #pragma unroll
  for (int g = 0; g < 8; ++g) qv4[g] = ((const float4*)qp)[g];

  const float* kb = kh + (size_t)bh * 2048 * 32;
  const float* vb = vh + (size_t)bh * 2048 * 32;

  // ---- pass A: M ----
  float M = -3.402823466e38f;
  for (int jc = 0; jc < 32; ++jc) {
    const float4* ksrc = (const float4*)(kb + (size_t)jc * 64 * 32);
    float4* kd = (float4*)ks;
    kd[t] = ksrc[t];
    kd[t + 256] = ksrc[t + 256];
    __syncthreads();
    #pragma unroll 4
    for (int k = 0; k < 16; ++k) {
      const float4* k4 = (const float4*)(ks + (w + 4 * k) * 32);
      float s = 0.f;
      #pragma unroll
      for (int g = 0; g < 8; ++g) {
        float4 kk = k4[g];
        s = fmaf(qv4[g].x, kk.x, s);
        s = fmaf(qv4[g].y, kk.y, s);
        s = fmaf(qv4[g].z, kk.z, s);
        s = fmaf(qv4[g].w, kk.w, s);
      }
      s = s / SCALE;
      M = fmaxf(M, s);
    }
    __syncthreads();
  }
  red[w][q] = M;
  __syncthreads();
  M = fmaxf(fmaxf(red[0][q], red[1][q]), fmaxf(red[2][q], red[3][q]));
  __syncthreads();

  // ---- pass B: L + PV (unnormalized), normalize at end ----
  float Lp = 0.f;
  float o[8];
  #pragma unroll
  for (int i = 0; i < 8; ++i) o[i] = 0.f;
  const int d0 = w * 8;
  for (int jc = 0; jc < 32; ++jc) {
    const float4* ksrc = (const float4*)(kb + (size_t)jc * 64 * 32);
    const float4* vsrc = (const float4*)(vb + (size_t)jc * 64 * 32);
    float4* kd = (float4*)ks;
    float4* vd = (float4*)vsd;
    kd[t] = ksrc[t];
    kd[t + 256] = ksrc[t + 256];
    vd[t] = vsrc[t];
    vd[t + 256] = vsrc[t + 256];
    __syncthreads();
    #pragma unroll 4
    for (int k = 0; k < 16; ++k) {
      int j = w + 4 * k;
      const float4* k4 = (const float4*)(ks + j * 32);
      float s = 0.f;
      #pragma unroll
      for (int g = 0; g < 8; ++g) {
        float4 kk = k4[g];
        s = fmaf(qv4[g].x, kk.x, s);
        s = fmaf(qv4[g].y, kk.y, s);
        s = fmaf(qv4[g].z, kk.z, s);
        s = fmaf(qv4[g].w, kk.w, s);
      }
      s = s / SCALE;
      float u = expf(s - M);
      sw[q * 65 + j] = u;
      Lp += u;
    }
    __syncthreads();
    #pragma unroll 4
    for (int j = 0; j < 64; ++j) {
      float u = sw[q * 65 + j];
      const float4* v4 = (const float4*)(vsd + j * 32 + d0);
      float4 va = v4[0], vb2 = v4[1];
      o[0] = fmaf(u, va.x,  o[0]);
      o[1] = fmaf(u, va.y,  o[1]);
      o[2] = fmaf(u, va.z,  o[2]);
      o[3] = fmaf(u, va.w,  o[3]);
      o[4] = fmaf(u, vb2.x, o[4]);
      o[5] = fmaf(u, vb2.y, o[5]);
      o[6] = fmaf(u, vb2.z, o[6]);
      o[7] = fmaf(u, vb2.w, o[7]);
    }
    __syncthreads();
  }
  red[w][q] = Lp;
  __syncthreads();
  float L = ((red[0][q] + red[1][q]) + red[2][q]) + red[3][q];
  int b = bh >> 3, hh = bh & 7, qg = qt * 64 + q;
  float* dst = oo + ((size_t)(b * 512 + qg)) * 256 + hh * 32 + d0;
  #pragma unroll
  for (int i = 0; i < 8; ++i) dst[i] = o[i] / L;
}

__global__ __launch_bounds__(256) void k_outproj(const float* __restrict__ oo,
    const float* __restrict__ wf, float* __restrict__ vsarr,
    const int* __restrict__ flags) {
  if (flags[0]) return;
  __shared__ float xs[16][256];
  const int t = threadIdx.x;
  const int n0 = blockIdx.x * 16;
  for (int r = 0; r < 16; ++r) xs[r][t] = oo[(size_t)(n0 + r) * 256 + t];
  __syncthreads();
  const float* wr = wf + W_OFF[9] + (size_t)t * 256;
  float acc[16];
  #pragma unroll
  for (int r = 0; r < 16; ++r) acc[r] = 0.f;
  for (int k = 0; k < 256; ++k) {
    float wk = wr[k];
    #pragma unroll
    for (int r = 0; r < 16; ++r) acc[r] = fmaf(xs[r][k], wk, acc[r]);
  }
  float bo = wf[W_OFF[10] + t];
  for (int r = 0; r < 16; ++r)
    vsarr[(size_t)(n0 + r) * 256 + t] = acc[r] + bo;
}

__global__ __launch_bounds__(256) void k_scores(const float* __restrict__ vsarr,
    const float* __restrict__ wf, const int* __restrict__ assign,
    float* __restrict__ sc, const int* __restrict__ flags) {
  if (flags[0]) return;
  __shared__ float xs[16][256];
  __shared__ float h[16][256];
  const int t = threadIdx.x;
  const int n0 = blockIdx.x * 16;
  for (int r = 0; r < 16; ++r) xs[r][t] = vsarr[(size_t)(n0 + r) * 256 + t];
  __syncthreads();
  const float* wr = wf + W_OFF[11] + (size_t)t * 256;
  float acc[16];
  #pragma unroll
  for (int r = 0; r < 16; ++r) acc[r] = 0.f;
  for (int k = 0; k < 256; ++k) {
    float wk = wr[k];
    #pragma unroll
    for (int r = 0; r < 16; ++r) acc[r] = fmaf(xs[r][k], wk, acc[r]);
  }
  float b1 = wf[W_OFF[12] + t];
  for (int r = 0; r < 16; ++r) h[r][t] = gelu_ref(acc[r] + b1);
  __syncthreads();
  if (t < 16) {
    const float* w2 = wf + W_OFF[13];
    float p = 0.f;
    for (int k = 0; k < 256; ++k) p = fmaf(h[t][k], w2[k], p);
    float s = p + wf[W_OFF[14]];
    int n = n0 + t;
    if (assign[n] != 2) s += -1e9f;
    sc[n] = s;
  }
}

__global__ __launch_bounds__(256) void k_select(const float* __restrict__ sc,
    const float* __restrict__ vsarr, const float* __restrict__ wf,
    int* __restrict__ assign, int* __restrict__ selb, int* __restrict__ flags) {
  if (flags[0]) return;
  const int b = blockIdx.x, t = threadIdx.x;
  __shared__ float sv[256];
  __shared__ int   si[256];
  float v0 = sc[b * 512 + t], v1 = sc[b * 512 + 256 + t];
  float bv; int bi;
  if (v1 > v0) { bv = v1; bi = t + 256; } else { bv = v0; bi = t; }
  sv[t] = bv; si[t] = bi;
  __syncthreads();
  for (int s = 128; s > 0; s >>= 1) {
    if (t < s) {
      float ov = sv[t + s]; int oi = si[t + s];
      if (ov > sv[t] || (ov == sv[t] && oi < si[t])) { sv[t] = ov; si[t] = oi; }
    }
    __syncthreads();
  }
  const int sel = si[0];
  __shared__ float x[256];
  __shared__ float h[256];
  x[t] = vsarr[((size_t)(b * 512 + sel)) * 256 + t];
  __syncthreads();
  const float* wr = wf + W_OFF[15] + (size_t)t * 256;
  float a = 0.f;
  for (int k = 0; k < 256; ++k) a = fmaf(x[k], wr[k], a);
  h[t] = gelu_ref(a + wf[W_OFF[16] + t]);
  __syncthreads();
  if (t == 0) {
    const float* w2 = wf + W_OFF[17];
    float l0 = 0.f, l1 = 0.f;
    for (int k = 0; k < 256; ++k) l0 = fmaf(h[k], w2[k], l0);
    for (int k = 0; k < 256; ++k) l1 = fmaf(h[k], w2[256 + k], l1);
    l0 += wf[W_OFF[18]];
    l1 += wf[W_OFF[18] + 1];
    int na = (l1 > l0) ? 1 : 0;
    assign[b * 512 + sel] = na;
    selb[b] = sel;
    if (b == 0) { flags[1] = 0; flags[2] = 0; }
  }
}

__global__ __launch_bounds__(256) void k_conflict(const int* __restrict__ formula,
    const int* __restrict__ assign, int* __restrict__ flags) {
  if (flags[0]) return;
  int idx = blockIdx.x * 256 + threadIdx.x;
  int b = idx >> 11;
  bool sat = false, alla = true;
  #pragma unroll
  for (int l = 0; l < 3; ++l) {
    int f = formula[idx * 3 + l];
    int a = assign[b * 512 + (f >> 1)];
    sat = sat || (a == (f & 1));
    alla = alla && (a != 2);
  }
  bool conf = alla && !sat;
  unsigned long long cb = __ballot(conf);
  int lane = threadIdx.x & 63;
  if (cb && lane == 0) atomicOr(&flags[1], 1);
  if (idx < 4096) {
    unsigned long long ub = __ballot(assign[idx] == 2);
    if (lane == 0 && ub) atomicAdd(&flags[2], (int)__popcll(ub));
  }
}

__global__ __launch_bounds__(64) void k_finalize(int* __restrict__ assign,
    const int* __restrict__ selb, int* __restrict__ flags) {
  if (flags[0]) return;
  int t = threadIdx.x;
  int ac = flags[1], ua = flags[2];
  if (ac && t < 8) assign[t * 512 + selb[t]] = 2;
  if (t == 0 && !ac && ua == 0) flags[0] = 1;
}

__global__ __launch_bounds__(256) void k_issat(const float* __restrict__ vsarr,
    const int* __restrict__ assign, const float* __restrict__ wf,
    void* __restrict__ outv, const int* __restrict__ dflag) {
  const int b = blockIdx.x, t = threadIdx.x;
  const int isf32 = dflag[0];
  __shared__ float x[256];
  __shared__ float h[256];
  float s = 0.f;
  for (int v = 0; v < 512; ++v) s += vsarr[((size_t)(b * 512 + v)) * 256 + t];
  x[t] = s / 512.0f;
  __syncthreads();
  const float* wr = wf + W_OFF[19] + (size_t)t * 256;
  float a = 0.f;
  for (int k = 0; k < 256; ++k) a = fmaf(x[k], wr[k], a);
  h[t] = gelu_ref(a + wf[W_OFF[20] + t]);
  __syncthreads();
  if (t == 0) {
    const float* w2 = wf + W_OFF[21];
    float l = 0.f;
    for (int k = 0; k < 256; ++k) l = fmaf(h[k], w2[k], l);
    l += wf[W_OFF[22]];
    float sig = 1.f / (1.f + expf(-l));
    if (isf32) ((float*)outv)[b] = sig;
    else ((__hip_bfloat16*)outv)[b] = __float2bfloat16(sig);
  }
  for (int i = t; i < 512; i += 256) {
    float av = (float)assign[b * 512 + i];
    if (isf32) ((float*)outv)[8 + b * 512 + i] = av;
    else ((__hip_bfloat16*)outv)[8 + b * 512 + i] = __float2bfloat16(av);
  }
}

extern "C" void kernel_launch(void* const* d_in, const int* in_sizes, int n_in,
                              void* d_out, int out_size, void* d_ws, size_t ws_size,
                              hipStream_t stream) {
  (void)in_sizes; (void)n_in; (void)out_size; (void)ws_size;
  const int* formula = (const int*)d_in[0];
  float* wf = (float*)d_ws;
  SrcPtrs sp;
  for (int i = 0; i < W_N; ++i) sp.p[i] = d_in[i + 1];
  float* base = wf + BASE_O;
  float* kh   = wf + KH_O;
  float* vh   = wf + VH_O;
  float* qh   = wf + QH_O;
  float* oo   = wf + OO_O;
  float* vs   = wf + VS_O;
  float* sc   = wf + SC_O;
  int* iw     = (int*)(wf + FTOT);
  int* assign = iw;
  int* selb   = iw + 4096;
  int* flags  = iw + 4104;
  int* dflag  = iw + 4107;

  k_detect<<<1, 256, 0, stream>>>((const unsigned short*)d_in[1], dflag);
  k_convert<<<(W_TOT + 255) / 256, 256, 0, stream>>>(sp, wf, dflag);
  k_init<<<4096, 256, 0, stream>>>(vs, assign, flags);
  k_base<<<1024, 256, 0, stream>>>(formula, wf, base);
  for (int it = 0; it < 8; ++it) {
    k_clause_kv<<<1024, 256, 0, stream>>>(formula, base, assign, wf, kh, vh, flags);
    k_q<<<256, 256, 0, stream>>>(vs, wf, qh, flags);
    k_attn<<<512, 256, 0, stream>>>(qh, kh, vh, oo, flags);
    k_outproj<<<256, 256, 0, stream>>>(oo, wf, vs, flags);
    k_scores<<<256, 256, 0, stream>>>(vs, wf, assign, sc, flags);
    k_select<<<8, 256, 0, stream>>>(sc, vs, wf, assign, selb, flags);
    k_conflict<<<64, 256, 0, stream>>>(formula, assign, flags);
    k_finalize<<<1, 64, 0, stream>>>(assign, selb, flags);
  }
  k_issat<<<8, 256, 0, stream>>>(vs, assign, wf, d_out, dflag);
}

// Round 5
// 4761.970 us; speedup vs baseline: 4.5737x; 1.3445x over previous
//
#include <hip/hip_runtime.h>
#include <hip/hip_bf16.h>

#pragma clang fp contract(off)

#define DEVI __device__ __forceinline__

constexpr int Bc = 8, Cc = 2048, Vc = 512, Hc = 256;

constexpr int W_N = 23;
constexpr int W_OFF[W_N] = {
  0,        524288,  655360,  655872,  656384,  656896,  787968,  788224,
  984832,   985600,  1051136, 1051392, 1116928, 1117184, 1117440, 1117444,
  1182980,  1183236, 1183748, 1183752, 1249288, 1249544, 1249800 };
constexpr int W_SZ[W_N] = {
  524288, 131072, 512, 512, 512, 131072, 256, 196608, 768,
  65536, 256, 65536, 256, 256, 1, 65536, 256, 512, 2, 65536, 256, 256, 1 };
constexpr int W_TOT = 1249804;
// slots: 0 lit_emb 1 ce_w1 2 ce_b1 3 ce_g 4 ce_beta 5 ce_w2 6 ce_b2
// 7 attn_in_w 8 attn_in_b 9 attn_out_w 10 attn_out_b 11 vs_w1 12 vs_b1
// 13 vs_w2 14 vs_b2 15 ap_w1 16 ap_b1 17 ap_w2 18 ap_b2 19 sp_w1 20 sp_b1
// 21 sp_w2 22 sp_b2

// transposed weight copies (coalesced GEMM reads), written once by k_transpose
constexpr size_t WT1_O   = 1249808;            // ce_w1^T   [256k][512r]
constexpr size_t WT2_O   = WT1_O   + 131072;   // ce_w2^T   [512k][256r]
constexpr size_t WTIN_O  = WT2_O   + 131072;   // attn_in^T [256k][768r]
constexpr size_t WTOUT_O = WTIN_O  + 196608;   // attn_out^T[256k][256r]
constexpr size_t WTV1_O  = WTOUT_O + 65536;    // vs_w1^T
constexpr size_t WTAP_O  = WTV1_O  + 65536;    // ap_w1^T
constexpr size_t WTSP_O  = WTAP_O  + 65536;    // sp_w1^T
constexpr size_t BASE_O  = WTSP_O  + 65536;
constexpr size_t KH_O    = BASE_O  + 4194304;
constexpr size_t VH_O    = KH_O    + 4194304;
constexpr size_t QH_O    = VH_O    + 4194304;
constexpr size_t OO_O    = QH_O    + 1048576;
constexpr size_t VS_O    = OO_O    + 1048576;
constexpr size_t SC_O    = VS_O    + 1048576;
constexpr size_t FTOT    = SC_O    + 4096;     // ~70.8 MB + int area

constexpr int T_N = 7;
constexpr int T_SRC[T_N]  = { 524288, 656896, 788224, 985600, 1051392, 1117444, 1183752 };
constexpr size_t T_DST[T_N] = { WT1_O, WT2_O, WTIN_O, WTOUT_O, WTV1_O, WTAP_O, WTSP_O };
constexpr int T_ROWS[T_N] = { 512, 256, 768, 256, 256, 256, 256 };
constexpr int T_L2C[T_N]  = { 8, 9, 8, 8, 8, 8, 8 };
constexpr int T_CUM[T_N + 1] = { 0, 131072, 262144, 458752, 524288, 589824, 655360, 720896 };

struct SrcPtrs { const void* p[W_N]; };

DEVI float gelu_ref(float x) {
  return (x * (erff(x / 1.41421356237309504880f) + 1.0f)) * 0.5f;
}

// ---------------- dtype probe ----------------
__global__ __launch_bounds__(256) void k_detect(const unsigned short* __restrict__ lit,
                                                int* __restrict__ dflag) {
  __shared__ int red[256];
  int t = threadIdx.x, c = 0;
  for (int i = t; i < 4096; i += 256) {
    unsigned e = (lit[i] >> 7) & 0xFF;
    if (e >= 0x8F) c++;
  }
  red[t] = c;
  __syncthreads();
  for (int s = 128; s > 0; s >>= 1) {
    if (t < s) red[t] += red[t + s];
    __syncthreads();
  }
  if (t == 0) dflag[0] = (red[0] > 64) ? 1 : 0;
}

__global__ __launch_bounds__(256) void k_convert(SrcPtrs sp, float* __restrict__ wf,
                                                 const int* __restrict__ dflag) {
  int idx = blockIdx.x * 256 + threadIdx.x;
  if (idx >= W_TOT) return;
  const int isf32 = dflag[0];
  int i = 0;
  while (i + 1 < W_N && idx >= W_OFF[i + 1]) i++;
  int j = idx - W_OFF[i];
  float v = 0.f;
  if (j < W_SZ[i]) {
    if (isf32) v = ((const float*)sp.p[i])[j];
    else {
      unsigned int u = (unsigned int)((const unsigned short*)sp.p[i])[j] << 16;
      v = __uint_as_float(u);
    }
  }
  wf[idx] = v;
}

__global__ __launch_bounds__(256) void k_transpose(float* __restrict__ wf) {
  int idx = blockIdx.x * 256 + threadIdx.x;
  if (idx >= T_CUM[T_N]) return;
  int mi = 0;
  while (mi + 1 < T_N && idx >= T_CUM[mi + 1]) mi++;
  int local = idx - T_CUM[mi];
  int cols = 1 << T_L2C[mi];
  int r = local >> T_L2C[mi];
  int c = local & (cols - 1);
  wf[T_DST[mi] + (size_t)c * T_ROWS[mi] + r] = wf[T_SRC[mi] + (size_t)local];
}

__global__ __launch_bounds__(256) void k_init(float* __restrict__ vsarr,
    int* __restrict__ assign, int* __restrict__ flags) {
  int idx = blockIdx.x * 256 + threadIdx.x;
  vsarr[idx] = 0.f;
  if (idx < 4096) assign[idx] = 2;
  if (idx < 3) flags[idx] = 0;
}

// ---------------- clause embedding (once) ----------------
__global__ __launch_bounds__(256) void k_base(const int* __restrict__ formula,
    const float* __restrict__ wf, float* __restrict__ base) {
  __shared__ float xs[16][256];
  __shared__ float h1[16][513];   // pad 513: serial LN loops become conflict-free
  __shared__ float mv[16], vr[16];
  const int t = threadIdx.x;
  const int n0 = blockIdx.x * 16;
  const float* lit = wf + W_OFF[0];
  for (int r = 0; r < 16; ++r) {
    int n = n0 + r;
    int f0 = formula[n*3+0], f1 = formula[n*3+1], f2 = formula[n*3+2];
    xs[r][t] = (lit[f0*256 + t] + lit[f1*256 + t] + lit[f2*256 + t]) / 3.0f;
  }
  __syncthreads();
  {
    const float* w1t = wf + WT1_O;   // [k][512r]
    float a0[16], a1[16];
    #pragma unroll
    for (int r = 0; r < 16; ++r) { a0[r] = 0.f; a1[r] = 0.f; }
    for (int k = 0; k < 256; ++k) {
      float wa = w1t[(size_t)k * 512 + t];
      float wb = w1t[(size_t)k * 512 + 256 + t];
      #pragma unroll
      for (int r = 0; r < 16; ++r) {
        a0[r] = fmaf(xs[r][k], wa, a0[r]);
        a1[r] = fmaf(xs[r][k], wb, a1[r]);
      }
    }
    float b0 = wf[W_OFF[2] + t], b1b = wf[W_OFF[2] + t + 256];
    #pragma unroll
    for (int r = 0; r < 16; ++r) {
      h1[r][t] = a0[r] + b0;
      h1[r][t + 256] = a1[r] + b1b;
    }
  }
  __syncthreads();
  if (t < 16) {
    float s = 0.f;
    for (int k = 0; k < 512; ++k) s += h1[t][k];
    float m = s / 512.0f;
    float v = 0.f;
    for (int k = 0; k < 512; ++k) { float d = h1[t][k] - m; float d2 = d * d; v += d2; }
    mv[t] = m; vr[t] = v / 512.0f;
  }
  __syncthreads();
  {
    const float* g  = wf + W_OFF[3];
    const float* be = wf + W_OFF[4];
    for (int r = 0; r < 16; ++r) {
      float sd = sqrtf(vr[r] + 1e-5f);
      for (int c = t; c < 512; c += 256) {
        float val = (h1[r][c] - mv[r]) / sd * g[c] + be[c];
        h1[r][c] = gelu_ref(val);
      }
    }
  }
  __syncthreads();
  {
    const float* w2t = wf + WT2_O;   // [k][256r]
    float acc[16];
    #pragma unroll
    for (int r = 0; r < 16; ++r) acc[r] = 0.f;
    for (int k = 0; k < 512; ++k) {
      float wk = w2t[(size_t)k * 256 + t];
      #pragma unroll
      for (int r = 0; r < 16; ++r) acc[r] = fmaf(h1[r][k], wk, acc[r]);
    }
    float b2 = wf[W_OFF[6] + t];
    for (int r = 0; r < 16; ++r)
      base[(size_t)(n0 + r) * 256 + t] = acc[r] + b2;
  }
}

// ---------------- per-iteration ----------------
__global__ __launch_bounds__(256) void k_clause_kv(const int* __restrict__ formula,
    const float* __restrict__ base, const int* __restrict__ assign,
    const float* __restrict__ wf, float* __restrict__ kh, float* __restrict__ vh,
    const int* __restrict__ flags) {
  if (flags[0]) return;
  __shared__ float xs[16][256];
  __shared__ float fac[16];
  const int t = threadIdx.x;
  const int n0 = blockIdx.x * 16;
  const int b = n0 / Cc;
  if (t < 16) {
    int n = n0 + t;
    bool sat = false;
    #pragma unroll
    for (int l = 0; l < 3; ++l) {
      int f = formula[n*3 + l];
      int a = assign[b * Vc + (f >> 1)];
      sat = sat || (a == (f & 1));
    }
    fac[t] = 1.0f - 0.9f * (sat ? 1.f : 0.f);
  }
  __syncthreads();
  for (int r = 0; r < 16; ++r)
    xs[r][t] = base[(size_t)(n0 + r) * 256 + t] * fac[r];
  __syncthreads();
  const float* wt = wf + WTIN_O;   // [k][768r]
  float aK[16], aV[16];
  #pragma unroll
  for (int r = 0; r < 16; ++r) { aK[r] = 0.f; aV[r] = 0.f; }
  for (int k = 0; k < 256; ++k) {
    float wa = wt[(size_t)k * 768 + 256 + t];
    float wb = wt[(size_t)k * 768 + 512 + t];
    #pragma unroll
    for (int r = 0; r < 16; ++r) {
      aK[r] = fmaf(xs[r][k], wa, aK[r]);
      aV[r] = fmaf(xs[r][k], wb, aV[r]);
    }
  }
  float bk = wf[W_OFF[8] + 256 + t], bv = wf[W_OFF[8] + 512 + t];
  int head = t >> 5, d = t & 31;
  float* kb = kh + (size_t)(b * 8 + head) * 2048 * 32;
  float* vb = vh + (size_t)(b * 8 + head) * 2048 * 32;
  int c0 = n0 - b * Cc;
  for (int r = 0; r < 16; ++r) {
    kb[(size_t)(c0 + r) * 32 + d] = aK[r] + bk;
    vb[(size_t)(c0 + r) * 32 + d] = aV[r] + bv;
  }
}

__global__ __launch_bounds__(256) void k_q(const float* __restrict__ vsarr,
    const float* __restrict__ wf, float* __restrict__ qh,
    const int* __restrict__ flags) {
  if (flags[0]) return;
  __shared__ float xs[16][256];
  const int t = threadIdx.x;
  const int n0 = blockIdx.x * 16;
  for (int r = 0; r < 16; ++r) xs[r][t] = vsarr[(size_t)(n0 + r) * 256 + t];
  __syncthreads();
  const float* wt = wf + WTIN_O;
  float acc[16];
  #pragma unroll
  for (int r = 0; r < 16; ++r) acc[r] = 0.f;
  for (int k = 0; k < 256; ++k) {
    float wk = wt[(size_t)k * 768 + t];
    #pragma unroll
    for (int r = 0; r < 16; ++r) acc[r] = fmaf(xs[r][k], wk, acc[r]);
  }
  float bq = wf[W_OFF[8] + t];
  int b = n0 / Vc, vloc = n0 % Vc;
  int head = t >> 5, d = t & 31;
  float* qb = qh + (size_t)(b * 8 + head) * 512 * 32;
  for (int r = 0; r < 16; ++r)
    qb[(size_t)(vloc + r) * 32 + d] = acc[r] + bq;
}

// ---- tiled exact-softmax attention ----
// block = (bh, 32-q tile); 256 threads = (w in [0,8)) x (q in [0,32)).
// 2-pass exact softmax; dot split into 4 fmaf chains (1-ulp reassociation,
// same class as the 8-way L sum). 1024 blocks -> 4 blocks/CU.
__global__ __launch_bounds__(256) void k_attn(const float* __restrict__ qh,
    const float* __restrict__ kh, const float* __restrict__ vh,
    float* __restrict__ oo, const int* __restrict__ flags) {
  if (flags[0]) return;
  __shared__ float ks[64 * 32];
  __shared__ float vsd[64 * 32];
  __shared__ float sw[32 * 65];
  __shared__ float red[8][32];
  const int blk = blockIdx.x;          // 1024 = 16 qt * 64 bh
  const int bh = blk & 63, qt = blk >> 6;
  const int t = threadIdx.x;
  const int w = t >> 5, q = t & 31;
  const float SCALE = 5.65685424949238019521f;  // f32(sqrt(32))

  const float* qp = qh + ((size_t)bh * 512 + qt * 32 + q) * 32;
  float4 qv4[8];
  #pragma unroll
  for (int g = 0; g < 8; ++g) qv4[g] = ((const float4*)qp)[g];

  const float* kb = kh + (size_t)bh * 2048 * 32;
  const float* vb = vh + (size_t)bh * 2048 * 32;

  // ---- pass A: M ----
  float M = -3.402823466e38f;
  for (int jc = 0; jc < 32; ++jc) {
    const float4* ksrc = (const float4*)(kb + (size_t)jc * 64 * 32);
    float4* kd = (float4*)ks;
    kd[t] = ksrc[t];
    kd[t + 256] = ksrc[t + 256];
    __syncthreads();
    #pragma unroll
    for (int kk = 0; kk < 8; ++kk) {
      const float4* k4 = (const float4*)(ks + (w + 8 * kk) * 32);
      float s0 = 0.f, s1 = 0.f, s2 = 0.f, s3 = 0.f;
      #pragma unroll
      for (int g = 0; g < 8; ++g) {
        float4 kv = k4[g];
        s0 = fmaf(qv4[g].x, kv.x, s0);
        s1 = fmaf(qv4[g].y, kv.y, s1);
        s2 = fmaf(qv4[g].z, kv.z, s2);
        s3 = fmaf(qv4[g].w, kv.w, s3);
      }
      float s = ((s0 + s1) + (s2 + s3)) / SCALE;
      M = fmaxf(M, s);
    }
    __syncthreads();
  }
  red[w][q] = M;
  __syncthreads();
  M = fmaxf(fmaxf(fmaxf(red[0][q], red[1][q]), fmaxf(red[2][q], red[3][q])),
            fmaxf(fmaxf(red[4][q], red[5][q]), fmaxf(red[6][q], red[7][q])));

  // ---- pass B: L + PV (unnormalized), normalize at end ----
  float Lp = 0.f;
  float o0 = 0.f, o1 = 0.f, o2 = 0.f, o3 = 0.f;
  const int d0 = w * 4;
  for (int jc = 0; jc < 32; ++jc) {
    const float4* ksrc = (const float4*)(kb + (size_t)jc * 64 * 32);
    const float4* vsrc = (const float4*)(vb + (size_t)jc * 64 * 32);
    float4* kd = (float4*)ks;
    float4* vd = (float4*)vsd;
    kd[t] = ksrc[t];
    kd[t + 256] = ksrc[t + 256];
    vd[t] = vsrc[t];
    vd[t + 256] = vsrc[t + 256];
    __syncthreads();
    #pragma unroll
    for (int kk = 0; kk < 8; ++kk) {
      int j = w + 8 * kk;
      const float4* k4 = (const float4*)(ks + j * 32);
      float s0 = 0.f, s1 = 0.f, s2 = 0.f, s3 = 0.f;
      #pragma unroll
      for (int g = 0; g < 8; ++g) {
        float4 kv = k4[g];
        s0 = fmaf(qv4[g].x, kv.x, s0);
        s1 = fmaf(qv4[g].y, kv.y, s1);
        s2 = fmaf(qv4[g].z, kv.z, s2);
        s3 = fmaf(qv4[g].w, kv.w, s3);
      }
      float s = ((s0 + s1) + (s2 + s3)) / SCALE;
      float u = expf(s - M);
      sw[q * 65 + j] = u;
      Lp += u;
    }
    __syncthreads();
    #pragma unroll 8
    for (int j = 0; j < 64; ++j) {
      float u = sw[q * 65 + j];
      float4 vv = *(const float4*)(vsd + j * 32 + d0);
      o0 = fmaf(u, vv.x, o0);
      o1 = fmaf(u, vv.y, o1);
      o2 = fmaf(u, vv.z, o2);
      o3 = fmaf(u, vv.w, o3);
    }
    __syncthreads();
  }
  red[w][q] = Lp;
  __syncthreads();
  float L = (((red[0][q] + red[1][q]) + (red[2][q] + red[3][q]))
           + ((red[4][q] + red[5][q]) + (red[6][q] + red[7][q])));
  int b = bh >> 3, hh = bh & 7, qg = qt * 32 + q;
  float* dst = oo + ((size_t)(b * 512 + qg)) * 256 + hh * 32 + d0;
  dst[0] = o0 / L; dst[1] = o1 / L; dst[2] = o2 / L; dst[3] = o3 / L;
}

__global__ __launch_bounds__(256) void k_outproj(const float* __restrict__ oo,
    const float* __restrict__ wf, float* __restrict__ vsarr,
    const int* __restrict__ flags) {
  if (flags[0]) return;
  __shared__ float xs[16][256];
  const int t = threadIdx.x;
  const int n0 = blockIdx.x * 16;
  for (int r = 0; r < 16; ++r) xs[r][t] = oo[(size_t)(n0 + r) * 256 + t];
  __syncthreads();
  const float* wt = wf + WTOUT_O;
  float acc[16];
  #pragma unroll
  for (int r = 0; r < 16; ++r) acc[r] = 0.f;
  for (int k = 0; k < 256; ++k) {
    float wk = wt[(size_t)k * 256 + t];
    #pragma unroll
    for (int r = 0; r < 16; ++r) acc[r] = fmaf(xs[r][k], wk, acc[r]);
  }
  float bo = wf[W_OFF[10] + t];
  for (int r = 0; r < 16; ++r)
    vsarr[(size_t)(n0 + r) * 256 + t] = acc[r] + bo;
}

__global__ __launch_bounds__(256) void k_scores(const float* __restrict__ vsarr,
    const float* __restrict__ wf, const int* __restrict__ assign,
    float* __restrict__ sc, const int* __restrict__ flags) {
  if (flags[0]) return;
  __shared__ float xs[16][256];
  __shared__ float h[16][256];
  const int t = threadIdx.x;
  const int n0 = blockIdx.x * 16;
  for (int r = 0; r < 16; ++r) xs[r][t] = vsarr[(size_t)(n0 + r) * 256 + t];
  __syncthreads();
  const float* wt = wf + WTV1_O;
  float acc[16];
  #pragma unroll
  for (int r = 0; r < 16; ++r) acc[r] = 0.f;
  for (int k = 0; k < 256; ++k) {
    float wk = wt[(size_t)k * 256 + t];
    #pragma unroll
    for (int r = 0; r < 16; ++r) acc[r] = fmaf(xs[r][k], wk, acc[r]);
  }
  float b1 = wf[W_OFF[12] + t];
  for (int r = 0; r < 16; ++r) h[r][t] = gelu_ref(acc[r] + b1);
  __syncthreads();
  if (t < 16) {
    const float* w2 = wf + W_OFF[13];
    float p = 0.f;
    for (int k = 0; k < 256; ++k) p = fmaf(h[t][k], w2[k], p);
    float s = p + wf[W_OFF[14]];
    int n = n0 + t;
    if (assign[n] != 2) s += -1e9f;
    sc[n] = s;
  }
}

__global__ __launch_bounds__(256) void k_select(const float* __restrict__ sc,
    const float* __restrict__ vsarr, const float* __restrict__ wf,
    int* __restrict__ assign, int* __restrict__ selb, int* __restrict__ flags) {
  if (flags[0]) return;
  const int b = blockIdx.x, t = threadIdx.x;
  __shared__ float sv[256];
  __shared__ int   si[256];
  float v0 = sc[b * 512 + t], v1 = sc[b * 512 + 256 + t];
  float bv; int bi;
  if (v1 > v0) { bv = v1; bi = t + 256; } else { bv = v0; bi = t; }
  sv[t] = bv; si[t] = bi;
  __syncthreads();
  for (int s = 128; s > 0; s >>= 1) {
    if (t < s) {
      float ov = sv[t + s]; int oi = si[t + s];
      if (ov > sv[t] || (ov == sv[t] && oi < si[t])) { sv[t] = ov; si[t] = oi; }
    }
    __syncthreads();
  }
  const int sel = si[0];
  __shared__ float x[256];
  __shared__ float h[256];
  x[t] = vsarr[((size_t)(b * 512 + sel)) * 256 + t];
  __syncthreads();
  const float* wt = wf + WTAP_O;
  float a = 0.f;
  for (int k = 0; k < 256; ++k) a = fmaf(x[k], wt[(size_t)k * 256 + t], a);
  h[t] = gelu_ref(a + wf[W_OFF[16] + t]);
  __syncthreads();
  if (t == 0) {
    const float* w2 = wf + W_OFF[17];
    float l0 = 0.f, l1 = 0.f;
    for (int k = 0; k < 256; ++k) l0 = fmaf(h[k], w2[k], l0);
    for (int k = 0; k < 256; ++k) l1 = fmaf(h[k], w2[256 + k], l1);
    l0 += wf[W_OFF[18]];
    l1 += wf[W_OFF[18] + 1];
    int na = (l1 > l0) ? 1 : 0;
    assign[b * 512 + sel] = na;
    selb[b] = sel;
  }
}

// fused conflict-check + revert + done-latch (single block)
__global__ __launch_bounds__(256) void k_conflict_fin(const int* __restrict__ formula,
    int* __restrict__ assign, const int* __restrict__ selb, int* __restrict__ flags) {
  if (flags[0]) return;
  __shared__ int sconf, suna;
  const int t = threadIdx.x;
  if (t == 0) { sconf = 0; suna = 0; }
  __syncthreads();
  int conf = 0;
  for (int i = t; i < 16384; i += 256) {
    int b = i >> 11;
    bool sat = false, alla = true;
    #pragma unroll
    for (int l = 0; l < 3; ++l) {
      int f = formula[i * 3 + l];
      int a = assign[b * 512 + (f >> 1)];
      sat = sat || (a == (f & 1));
      alla = alla && (a != 2);
    }
    if (alla && !sat) conf = 1;
  }
  if (conf) atomicOr(&sconf, 1);
  int una = 0;
  for (int i = t; i < 4096; i += 256)
    if (assign[i] == 2) una = 1;
  if (una) atomicOr(&suna, 1);
  __syncthreads();
  if (sconf) {
    if (t < 8) assign[t * 512 + selb[t]] = 2;
  } else if (t == 0 && suna == 0) {
    flags[0] = 1;
  }
}

__global__ __launch_bounds__(256) void k_issat(const float* __restrict__ vsarr,
    const int* __restrict__ assign, const float* __restrict__ wf,
    void* __restrict__ outv, const int* __restrict__ dflag) {
  const int b = blockIdx.x, t = threadIdx.x;
  const int isf32 = dflag[0];
  __shared__ float x[256];
  __shared__ float h[256];
  float s = 0.f;
  for (int v = 0; v < 512; ++v) s += vsarr[((size_t)(b * 512 + v)) * 256 + t];
  x[t] = s / 512.0f;
  __syncthreads();
  const float* wt = wf + WTSP_O;
  float a = 0.f;
  for (int k = 0; k < 256; ++k) a = fmaf(x[k], wt[(size_t)k * 256 + t], a);
  h[t] = gelu_ref(a + wf[W_OFF[20] + t]);
  __syncthreads();
  if (t == 0) {
    const float* w2 = wf + W_OFF[21];
    float l = 0.f;
    for (int k = 0; k < 256; ++k) l = fmaf(h[k], w2[k], l);
    l += wf[W_OFF[22]];
    float sig = 1.f / (1.f + expf(-l));
    if (isf32) ((float*)outv)[b] = sig;
    else ((__hip_bfloat16*)outv)[b] = __float2bfloat16(sig);
  }
  for (int i = t; i < 512; i += 256) {
    float av = (float)assign[b * 512 + i];
    if (isf32) ((float*)outv)[8 + b * 512 + i] = av;
    else ((__hip_bfloat16*)outv)[8 + b * 512 + i] = __float2bfloat16(av);
  }
}

extern "C" void kernel_launch(void* const* d_in, const int* in_sizes, int n_in,
                              void* d_out, int out_size, void* d_ws, size_t ws_size,
                              hipStream_t stream) {
  (void)in_sizes; (void)n_in; (void)out_size; (void)ws_size;
  const int* formula = (const int*)d_in[0];
  float* wf = (float*)d_ws;
  SrcPtrs sp;
  for (int i = 0; i < W_N; ++i) sp.p[i] = d_in[i + 1];
  float* base = wf + BASE_O;
  float* kh   = wf + KH_O;
  float* vh   = wf + VH_O;
  float* qh   = wf + QH_O;
  float* oo   = wf + OO_O;
  float* vs   = wf + VS_O;
  float* sc   = wf + SC_O;
  int* iw     = (int*)(wf + FTOT);
  int* assign = iw;
  int* selb   = iw + 4096;
  int* flags  = iw + 4104;
  int* dflag  = iw + 4107;

  k_detect<<<1, 256, 0, stream>>>((const unsigned short*)d_in[1], dflag);
  k_convert<<<(W_TOT + 255) / 256, 256, 0, stream>>>(sp, wf, dflag);
  k_transpose<<<(T_CUM[T_N] + 255) / 256, 256, 0, stream>>>(wf);
  k_init<<<4096, 256, 0, stream>>>(vs, assign, flags);
  k_base<<<1024, 256, 0, stream>>>(formula, wf, base);
  for (int it = 0; it < 8; ++it) {
    k_clause_kv<<<1024, 256, 0, stream>>>(formula, base, assign, wf, kh, vh, flags);
    k_q<<<256, 256, 0, stream>>>(vs, wf, qh, flags);
    k_attn<<<1024, 256, 0, stream>>>(qh, kh, vh, oo, flags);
    k_outproj<<<256, 256, 0, stream>>>(oo, wf, vs, flags);
    k_scores<<<256, 256, 0, stream>>>(vs, wf, assign, sc, flags);
    k_select<<<8, 256, 0, stream>>>(sc, vs, wf, assign, selb, flags);
    k_conflict_fin<<<1, 256, 0, stream>>>(formula, assign, selb, flags);
  }
  k_issat<<<8, 256, 0, stream>>>(vs, assign, wf, d_out, dflag);
}

// Round 6
// 3999.583 us; speedup vs baseline: 5.4455x; 1.1906x over previous
//
#include <hip/hip_runtime.h>
#include <hip/hip_bf16.h>

#pragma clang fp contract(off)

#define DEVI __device__ __forceinline__

constexpr int Bc = 8, Cc = 2048, Vc = 512, Hc = 256;

constexpr int W_N = 23;
constexpr int W_OFF[W_N] = {
  0,        524288,  655360,  655872,  656384,  656896,  787968,  788224,
  984832,   985600,  1051136, 1051392, 1116928, 1117184, 1117440, 1117444,
  1182980,  1183236, 1183748, 1183752, 1249288, 1249544, 1249800 };
constexpr int W_SZ[W_N] = {
  524288, 131072, 512, 512, 512, 131072, 256, 196608, 768,
  65536, 256, 65536, 256, 256, 1, 65536, 256, 512, 2, 65536, 256, 256, 1 };
constexpr int W_TOT = 1249804;
// slots: 0 lit_emb 1 ce_w1 2 ce_b1 3 ce_g 4 ce_beta 5 ce_w2 6 ce_b2
// 7 attn_in_w 8 attn_in_b 9 attn_out_w 10 attn_out_b 11 vs_w1 12 vs_b1
// 13 vs_w2 14 vs_b2 15 ap_w1 16 ap_b1 17 ap_w2 18 ap_b2 19 sp_w1 20 sp_b1
// 21 sp_w2 22 sp_b2

constexpr size_t WT1_O   = 1249808;            // ce_w1^T   [256k][512r]
constexpr size_t WT2_O   = WT1_O   + 131072;   // ce_w2^T   [512k][256r]
constexpr size_t WTIN_O  = WT2_O   + 131072;   // attn_in^T [256k][768r]
constexpr size_t WTOUT_O = WTIN_O  + 196608;   // attn_out^T[256k][256r]
constexpr size_t WTV1_O  = WTOUT_O + 65536;    // vs_w1^T
constexpr size_t WTAP_O  = WTV1_O  + 65536;    // ap_w1^T
constexpr size_t WTSP_O  = WTAP_O  + 65536;    // sp_w1^T
constexpr size_t BASE_O  = WTSP_O  + 65536;
constexpr size_t KH_O    = BASE_O  + 4194304;
constexpr size_t VH_O    = KH_O    + 4194304;
constexpr size_t QH_O    = VH_O    + 4194304;
constexpr size_t OO_O    = QH_O    + 1048576;
constexpr size_t VS_O    = OO_O    + 1048576;
constexpr size_t SC_O    = VS_O    + 1048576;
constexpr size_t FTOT    = SC_O    + 4096;

constexpr int T_N = 7;
constexpr int T_SRC[T_N]  = { 524288, 656896, 788224, 985600, 1051392, 1117444, 1183752 };
constexpr size_t T_DST[T_N] = { WT1_O, WT2_O, WTIN_O, WTOUT_O, WTV1_O, WTAP_O, WTSP_O };
constexpr int T_ROWS[T_N] = { 512, 256, 768, 256, 256, 256, 256 };
constexpr int T_L2C[T_N]  = { 8, 9, 8, 8, 8, 8, 8 };
constexpr int T_CUM[T_N + 1] = { 0, 131072, 262144, 458752, 524288, 589824, 655360, 720896 };

struct SrcPtrs { const void* p[W_N]; };

DEVI float gelu_ref(float x) {
  return (x * (erff(x / 1.41421356237309504880f) + 1.0f)) * 0.5f;
}

__global__ __launch_bounds__(256) void k_detect(const unsigned short* __restrict__ lit,
                                                int* __restrict__ dflag) {
  __shared__ int red[256];
  int t = threadIdx.x, c = 0;
  for (int i = t; i < 4096; i += 256) {
    unsigned e = (lit[i] >> 7) & 0xFF;
    if (e >= 0x8F) c++;
  }
  red[t] = c;
  __syncthreads();
  for (int s = 128; s > 0; s >>= 1) {
    if (t < s) red[t] += red[t + s];
    __syncthreads();
  }
  if (t == 0) dflag[0] = (red[0] > 64) ? 1 : 0;
}

__global__ __launch_bounds__(256) void k_convert(SrcPtrs sp, float* __restrict__ wf,
                                                 const int* __restrict__ dflag) {
  int idx = blockIdx.x * 256 + threadIdx.x;
  if (idx >= W_TOT) return;
  const int isf32 = dflag[0];
  int i = 0;
  while (i + 1 < W_N && idx >= W_OFF[i + 1]) i++;
  int j = idx - W_OFF[i];
  float v = 0.f;
  if (j < W_SZ[i]) {
    if (isf32) v = ((const float*)sp.p[i])[j];
    else {
      unsigned int u = (unsigned int)((const unsigned short*)sp.p[i])[j] << 16;
      v = __uint_as_float(u);
    }
  }
  wf[idx] = v;
}

__global__ __launch_bounds__(256) void k_transpose(float* __restrict__ wf) {
  int idx = blockIdx.x * 256 + threadIdx.x;
  if (idx >= T_CUM[T_N]) return;
  int mi = 0;
  while (mi + 1 < T_N && idx >= T_CUM[mi + 1]) mi++;
  int local = idx - T_CUM[mi];
  int cols = 1 << T_L2C[mi];
  int r = local >> T_L2C[mi];
  int c = local & (cols - 1);
  wf[T_DST[mi] + (size_t)c * T_ROWS[mi] + r] = wf[T_SRC[mi] + (size_t)local];
}

__global__ __launch_bounds__(256) void k_init(float* __restrict__ vsarr,
    int* __restrict__ assign, int* __restrict__ flags) {
  int idx = blockIdx.x * 256 + threadIdx.x;
  vsarr[idx] = 0.f;
  if (idx < 4096) assign[idx] = 2;
  if (idx < 3) flags[idx] = 0;
}

__global__ __launch_bounds__(256) void k_base(const int* __restrict__ formula,
    const float* __restrict__ wf, float* __restrict__ base) {
  __shared__ float xs[16][256];
  __shared__ float h1[16][513];
  __shared__ float mv[16], vr[16];
  const int t = threadIdx.x;
  const int n0 = blockIdx.x * 16;
  const float* lit = wf + W_OFF[0];
  for (int r = 0; r < 16; ++r) {
    int n = n0 + r;
    int f0 = formula[n*3+0], f1 = formula[n*3+1], f2 = formula[n*3+2];
    xs[r][t] = (lit[f0*256 + t] + lit[f1*256 + t] + lit[f2*256 + t]) / 3.0f;
  }
  __syncthreads();
  {
    const float* w1t = wf + WT1_O;
    float a0[16], a1[16];
    #pragma unroll
    for (int r = 0; r < 16; ++r) { a0[r] = 0.f; a1[r] = 0.f; }
    for (int k = 0; k < 256; ++k) {
      float wa = w1t[(size_t)k * 512 + t];
      float wb = w1t[(size_t)k * 512 + 256 + t];
      #pragma unroll
      for (int r = 0; r < 16; ++r) {
        a0[r] = fmaf(xs[r][k], wa, a0[r]);
        a1[r] = fmaf(xs[r][k], wb, a1[r]);
      }
    }
    float b0 = wf[W_OFF[2] + t], b1b = wf[W_OFF[2] + t + 256];
    #pragma unroll
    for (int r = 0; r < 16; ++r) {
      h1[r][t] = a0[r] + b0;
      h1[r][t + 256] = a1[r] + b1b;
    }
  }
  __syncthreads();
  if (t < 16) {
    float s = 0.f;
    for (int k = 0; k < 512; ++k) s += h1[t][k];
    float m = s / 512.0f;
    float v = 0.f;
    for (int k = 0; k < 512; ++k) { float d = h1[t][k] - m; float d2 = d * d; v += d2; }
    mv[t] = m; vr[t] = v / 512.0f;
  }
  __syncthreads();
  {
    const float* g  = wf + W_OFF[3];
    const float* be = wf + W_OFF[4];
    for (int r = 0; r < 16; ++r) {
      float sd = sqrtf(vr[r] + 1e-5f);
      for (int c = t; c < 512; c += 256) {
        float val = (h1[r][c] - mv[r]) / sd * g[c] + be[c];
        h1[r][c] = gelu_ref(val);
      }
    }
  }
  __syncthreads();
  {
    const float* w2t = wf + WT2_O;
    float acc[16];
    #pragma unroll
    for (int r = 0; r < 16; ++r) acc[r] = 0.f;
    for (int k = 0; k < 512; ++k) {
      float wk = w2t[(size_t)k * 256 + t];
      #pragma unroll
      for (int r = 0; r < 16; ++r) acc[r] = fmaf(h1[r][k], wk, acc[r]);
    }
    float b2 = wf[W_OFF[6] + t];
    for (int r = 0; r < 16; ++r)
      base[(size_t)(n0 + r) * 256 + t] = acc[r] + b2;
  }
}

__global__ __launch_bounds__(256) void k_clause_kv(const int* __restrict__ formula,
    const float* __restrict__ base, const int* __restrict__ assign,
    const float* __restrict__ wf, float* __restrict__ kh, float* __restrict__ vh,
    const int* __restrict__ flags) {
  if (flags[0]) return;
  __shared__ float xs[16][256];
  __shared__ float fac[16];
  const int t = threadIdx.x;
  const int n0 = blockIdx.x * 16;
  const int b = n0 / Cc;
  if (t < 16) {
    int n = n0 + t;
    bool sat = false;
    #pragma unroll
    for (int l = 0; l < 3; ++l) {
      int f = formula[n*3 + l];
      int a = assign[b * Vc + (f >> 1)];
      sat = sat || (a == (f & 1));
    }
    fac[t] = 1.0f - 0.9f * (sat ? 1.f : 0.f);
  }
  __syncthreads();
  for (int r = 0; r < 16; ++r)
    xs[r][t] = base[(size_t)(n0 + r) * 256 + t] * fac[r];
  __syncthreads();
  const float* wt = wf + WTIN_O;
  float aK[16], aV[16];
  #pragma unroll
  for (int r = 0; r < 16; ++r) { aK[r] = 0.f; aV[r] = 0.f; }
  for (int k = 0; k < 256; ++k) {
    float wa = wt[(size_t)k * 768 + 256 + t];
    float wb = wt[(size_t)k * 768 + 512 + t];
    #pragma unroll
    for (int r = 0; r < 16; ++r) {
      aK[r] = fmaf(xs[r][k], wa, aK[r]);
      aV[r] = fmaf(xs[r][k], wb, aV[r]);
    }
  }
  float bk = wf[W_OFF[8] + 256 + t], bv = wf[W_OFF[8] + 512 + t];
  int head = t >> 5, d = t & 31;
  float* kb = kh + (size_t)(b * 8 + head) * 2048 * 32;
  float* vb = vh + (size_t)(b * 8 + head) * 2048 * 32;
  int c0 = n0 - b * Cc;
  for (int r = 0; r < 16; ++r) {
    kb[(size_t)(c0 + r) * 32 + d] = aK[r] + bk;
    vb[(size_t)(c0 + r) * 32 + d] = aV[r] + bv;
  }
}

__global__ __launch_bounds__(256) void k_q(const float* __restrict__ vsarr,
    const float* __restrict__ wf, float* __restrict__ qh,
    const int* __restrict__ flags) {
  if (flags[0]) return;
  __shared__ float xs[16][256];
  const int t = threadIdx.x;
  const int n0 = blockIdx.x * 16;
  for (int r = 0; r < 16; ++r) xs[r][t] = vsarr[(size_t)(n0 + r) * 256 + t];
  __syncthreads();
  const float* wt = wf + WTIN_O;
  float acc[16];
  #pragma unroll
  for (int r = 0; r < 16; ++r) acc[r] = 0.f;
  for (int k = 0; k < 256; ++k) {
    float wk = wt[(size_t)k * 768 + t];
    #pragma unroll
    for (int r = 0; r < 16; ++r) acc[r] = fmaf(xs[r][k], wk, acc[r]);
  }
  float bq = wf[W_OFF[8] + t];
  int b = n0 / Vc, vloc = n0 % Vc;
  int head = t >> 5, d = t & 31;
  float* qb = qh + (size_t)(b * 8 + head) * 512 * 32;
  for (int r = 0; r < 16; ++r)
    qb[(size_t)(vloc + r) * 32 + d] = acc[r] + bq;
}

// ---- tiled exact-softmax attention v3 ----
__global__ __launch_bounds__(256) void k_attn(const float* __restrict__ qh,
    const float* __restrict__ kh, const float* __restrict__ vh,
    float* __restrict__ oo, const int* __restrict__ flags) {
  if (flags[0]) return;
  __shared__ __align__(16) float kT[32 * 68];
  __shared__ __align__(16) float vsd[64 * 32];
  __shared__ __align__(16) float su[32 * 68];
  __shared__ float mred[32 * 17];
  const int blk = blockIdx.x;          // 1024 = 16 qt * 64 bh
  const int bh = blk & 63, qt = blk >> 6;
  const int t = threadIdx.x;
  const int tq = t >> 4, tj = t & 15;
  const int q0 = tq * 2, j0 = tj * 4;
  const float INV = 0.17677669529663687f;  // f32(1/sqrt(32))

  float qv[2][32];
  {
    const float4* qp0 = (const float4*)(qh + ((size_t)bh * 512 + qt * 32 + q0) * 32);
    const float4* qp1 = (const float4*)(qh + ((size_t)bh * 512 + qt * 32 + q0 + 1) * 32);
    #pragma unroll
    for (int g = 0; g < 8; ++g) {
      float4 a = qp0[g]; float4 b = qp1[g];
      qv[0][4*g+0]=a.x; qv[0][4*g+1]=a.y; qv[0][4*g+2]=a.z; qv[0][4*g+3]=a.w;
      qv[1][4*g+0]=b.x; qv[1][4*g+1]=b.y; qv[1][4*g+2]=b.z; qv[1][4*g+3]=b.w;
    }
  }
  const float* kb = kh + (size_t)bh * 2048 * 32;
  const float* vb = vh + (size_t)bh * 2048 * 32;
  const int sj = t >> 2, sd8 = (t & 3) * 2;

  // ---- pass A: exact row max ----
  float M0 = -3.402823466e38f, M1 = -3.402823466e38f;
  for (int jc = 0; jc < 32; ++jc) {
    const float4* ksrc = (const float4*)(kb + (size_t)jc * 64 * 32);
    float4 ka = ksrc[sj * 8 + sd8];
    float4 kb4 = ksrc[sj * 8 + sd8 + 1];
    int dbase = sd8 * 4;
    kT[(dbase+0)*68 + sj] = ka.x;  kT[(dbase+1)*68 + sj] = ka.y;
    kT[(dbase+2)*68 + sj] = ka.z;  kT[(dbase+3)*68 + sj] = ka.w;
    kT[(dbase+4)*68 + sj] = kb4.x; kT[(dbase+5)*68 + sj] = kb4.y;
    kT[(dbase+6)*68 + sj] = kb4.z; kT[(dbase+7)*68 + sj] = kb4.w;
    __syncthreads();
    float a00=0.f,a01=0.f,a02=0.f,a03=0.f;
    float a10=0.f,a11=0.f,a12=0.f,a13=0.f;
    #pragma unroll
    for (int d = 0; d < 32; ++d) {
      float4 kk = *(const float4*)&kT[d * 68 + j0];
      float qa = qv[0][d], qb2 = qv[1][d];
      a00 = fmaf(qa, kk.x, a00); a01 = fmaf(qa, kk.y, a01);
      a02 = fmaf(qa, kk.z, a02); a03 = fmaf(qa, kk.w, a03);
      a10 = fmaf(qb2, kk.x, a10); a11 = fmaf(qb2, kk.y, a11);
      a12 = fmaf(qb2, kk.z, a12); a13 = fmaf(qb2, kk.w, a13);
    }
    M0 = fmaxf(M0, fmaxf(fmaxf(a00*INV, a01*INV), fmaxf(a02*INV, a03*INV)));
    M1 = fmaxf(M1, fmaxf(fmaxf(a10*INV, a11*INV), fmaxf(a12*INV, a13*INV)));
    __syncthreads();
  }
  mred[(q0+0)*17 + tj] = M0;
  mred[(q0+1)*17 + tj] = M1;
  __syncthreads();
  M0 = mred[(q0+0)*17]; M1 = mred[(q0+1)*17];
  #pragma unroll
  for (int i = 1; i < 16; ++i) {
    M0 = fmaxf(M0, mred[(q0+0)*17 + i]);
    M1 = fmaxf(M1, mred[(q0+1)*17 + i]);
  }
  __syncthreads();

  // ---- pass B: L + PV (unnormalized), normalize at end ----
  float Lp0 = 0.f, Lp1 = 0.f;
  const int qp = t >> 3, d0v = (t & 7) * 4;
  float o0=0.f,o1=0.f,o2=0.f,o3=0.f;
  for (int jc = 0; jc < 32; ++jc) {
    const float4* ksrc = (const float4*)(kb + (size_t)jc * 64 * 32);
    const float4* vsrc = (const float4*)(vb + (size_t)jc * 64 * 32);
    float4 ka = ksrc[sj * 8 + sd8];
    float4 kb4 = ksrc[sj * 8 + sd8 + 1];
    int dbase = sd8 * 4;
    kT[(dbase+0)*68 + sj] = ka.x;  kT[(dbase+1)*68 + sj] = ka.y;
    kT[(dbase+2)*68 + sj] = ka.z;  kT[(dbase+3)*68 + sj] = ka.w;
    kT[(dbase+4)*68 + sj] = kb4.x; kT[(dbase+5)*68 + sj] = kb4.y;
    kT[(dbase+6)*68 + sj] = kb4.z; kT[(dbase+7)*68 + sj] = kb4.w;
    float4* vd = (float4*)vsd;
    vd[t] = vsrc[t];
    vd[t + 256] = vsrc[t + 256];
    __syncthreads();
    float a00=0.f,a01=0.f,a02=0.f,a03=0.f;
    float a10=0.f,a11=0.f,a12=0.f,a13=0.f;
    #pragma unroll
    for (int d = 0; d < 32; ++d) {
      float4 kk = *(const float4*)&kT[d * 68 + j0];
      float qa = qv[0][d], qb2 = qv[1][d];
      a00 = fmaf(qa, kk.x, a00); a01 = fmaf(qa, kk.y, a01);
      a02 = fmaf(qa, kk.z, a02); a03 = fmaf(qa, kk.w, a03);
      a10 = fmaf(qb2, kk.x, a10); a11 = fmaf(qb2, kk.y, a11);
      a12 = fmaf(qb2, kk.z, a12); a13 = fmaf(qb2, kk.w, a13);
    }
    float u00 = expf(a00*INV - M0), u01 = expf(a01*INV - M0);
    float u02 = expf(a02*INV - M0), u03 = expf(a03*INV - M0);
    float u10 = expf(a10*INV - M1), u11 = expf(a11*INV - M1);
    float u12 = expf(a12*INV - M1), u13 = expf(a13*INV - M1);
    float4 w0; w0.x=u00; w0.y=u01; w0.z=u02; w0.w=u03;
    float4 w1; w1.x=u10; w1.y=u11; w1.z=u12; w1.w=u13;
    *(float4*)&su[(q0+0)*68 + j0] = w0;
    *(float4*)&su[(q0+1)*68 + j0] = w1;
    Lp0 += ((u00 + u01) + (u02 + u03));
    Lp1 += ((u10 + u11) + (u12 + u13));
    __syncthreads();
    #pragma unroll
    for (int jq = 0; jq < 16; ++jq) {
      float4 uu = *(const float4*)&su[qp * 68 + jq * 4];
      float4 v0 = *(const float4*)&vsd[(jq*4+0)*32 + d0v];
      float4 v1 = *(const float4*)&vsd[(jq*4+1)*32 + d0v];
      float4 v2 = *(const float4*)&vsd[(jq*4+2)*32 + d0v];
      float4 v3 = *(const float4*)&vsd[(jq*4+3)*32 + d0v];
      o0 = fmaf(uu.x, v0.x, o0); o1 = fmaf(uu.x, v0.y, o1);
      o2 = fmaf(uu.x, v0.z, o2); o3 = fmaf(uu.x, v0.w, o3);
      o0 = fmaf(uu.y, v1.x, o0); o1 = fmaf(uu.y, v1.y, o1);
      o2 = fmaf(uu.y, v1.z, o2); o3 = fmaf(uu.y, v1.w, o3);
      o0 = fmaf(uu.z, v2.x, o0); o1 = fmaf(uu.z, v2.y, o1);
      o2 = fmaf(uu.z, v2.z, o2); o3 = fmaf(uu.z, v2.w, o3);
      o0 = fmaf(uu.w, v3.x, o0); o1 = fmaf(uu.w, v3.y, o1);
      o2 = fmaf(uu.w, v3.z, o2); o3 = fmaf(uu.w, v3.w, o3);
    }
    __syncthreads();
  }
  mred[(q0+0)*17 + tj] = Lp0;
  mred[(q0+1)*17 + tj] = Lp1;
  __syncthreads();
  float L = mred[qp * 17];
  #pragma unroll
  for (int i = 1; i < 16; ++i) L += mred[qp * 17 + i];
  int b = bh >> 3, hh = bh & 7, qg = qt * 32 + qp;
  float4 r;
  r.x = o0 / L; r.y = o1 / L; r.z = o2 / L; r.w = o3 / L;
  *(float4*)(oo + ((size_t)(b * 512 + qg)) * 256 + hh * 32 + d0v) = r;
}

__global__ __launch_bounds__(256) void k_outproj(const float* __restrict__ oo,
    const float* __restrict__ wf, float* __restrict__ vsarr,
    const int* __restrict__ flags) {
  if (flags[0]) return;
  __shared__ float xs[16][256];
  const int t = threadIdx.x;
  const int n0 = blockIdx.x * 16;
  for (int r = 0; r < 16; ++r) xs[r][t] = oo[(size_t)(n0 + r) * 256 + t];
  __syncthreads();
  const float* wt = wf + WTOUT_O;
  float acc[16];
  #pragma unroll
  for (int r = 0; r < 16; ++r) acc[r] = 0.f;
  for (int k = 0; k < 256; ++k) {
    float wk = wt[(size_t)k * 256 + t];
    #pragma unroll
    for (int r = 0; r < 16; ++r) acc[r] = fmaf(xs[r][k], wk, acc[r]);
  }
  float bo = wf[W_OFF[10] + t];
  for (int r = 0; r < 16; ++r)
    vsarr[(size_t)(n0 + r) * 256 + t] = acc[r] + bo;
}

__global__ __launch_bounds__(256) void k_scores(const float* __restrict__ vsarr,
    const float* __restrict__ wf, const int* __restrict__ assign,
    float* __restrict__ sc, const int* __restrict__ flags) {
  if (flags[0]) return;
  __shared__ float xs[16][256];
  __shared__ float h[16][256];
  const int t = threadIdx.x;
  const int n0 = blockIdx.x * 16;
  for (int r = 0; r < 16; ++r) xs[r][t] = vsarr[(size_t)(n0 + r) * 256 + t];
  __syncthreads();
  const float* wt = wf + WTV1_O;
  float acc[16];
  #pragma unroll
  for (int r = 0; r < 16; ++r) acc[r] = 0.f;
  for (int k = 0; k < 256; ++k) {
    float wk = wt[(size_t)k * 256 + t];
    #pragma unroll
    for (int r = 0; r < 16; ++r) acc[r] = fmaf(xs[r][k], wk, acc[r]);
  }
  float b1 = wf[W_OFF[12] + t];
  for (int r = 0; r < 16; ++r) h[r][t] = gelu_ref(acc[r] + b1);
  __syncthreads();
  if (t < 16) {
    const float* w2 = wf + W_OFF[13];
    float p = 0.f;
    for (int k = 0; k < 256; ++k) p = fmaf(h[t][k], w2[k], p);
    float s = p + wf[W_OFF[14]];
    int n = n0 + t;
    if (assign[n] != 2) s += -1e9f;
    sc[n] = s;
  }
}

__global__ __launch_bounds__(256) void k_select(const float* __restrict__ sc,
    const float* __restrict__ vsarr, const float* __restrict__ wf,
    int* __restrict__ assign, int* __restrict__ selb, int* __restrict__ flags) {
  if (flags[0]) return;
  const int b = blockIdx.x, t = threadIdx.x;
  __shared__ float sv[256];
  __shared__ int   si[256];
  float v0 = sc[b * 512 + t], v1 = sc[b * 512 + 256 + t];
  float bv; int bi;
  if (v1 > v0) { bv = v1; bi = t + 256; } else { bv = v0; bi = t; }
  sv[t] = bv; si[t] = bi;
  __syncthreads();
  for (int s = 128; s > 0; s >>= 1) {
    if (t < s) {
      float ov = sv[t + s]; int oi = si[t + s];
      if (ov > sv[t] || (ov == sv[t] && oi < si[t])) { sv[t] = ov; si[t] = oi; }
    }
    __syncthreads();
  }
  const int sel = si[0];
  __shared__ float x[256];
  __shared__ float h[256];
  x[t] = vsarr[((size_t)(b * 512 + sel)) * 256 + t];
  __syncthreads();
  const float* wt = wf + WTAP_O;
  float a = 0.f;
  for (int k = 0; k < 256; ++k) a = fmaf(x[k], wt[(size_t)k * 256 + t], a);
  h[t] = gelu_ref(a + wf[W_OFF[16] + t]);
  __syncthreads();
  if (t == 0) {
    const float* w2 = wf + W_OFF[17];
    float l0 = 0.f, l1 = 0.f;
    for (int k = 0; k < 256; ++k) l0 = fmaf(h[k], w2[k], l0);
    for (int k = 0; k < 256; ++k) l1 = fmaf(h[k], w2[256 + k], l1);
    l0 += wf[W_OFF[18]];
    l1 += wf[W_OFF[18] + 1];
    int na = (l1 > l0) ? 1 : 0;
    assign[b * 512 + sel] = na;
    selb[b] = sel;
  }
}

__global__ __launch_bounds__(256) void k_conflict_fin(const int* __restrict__ formula,
    int* __restrict__ assign, const int* __restrict__ selb, int* __restrict__ flags) {
  if (flags[0]) return;
  __shared__ int sconf, suna;
  const int t = threadIdx.x;
  if (t == 0) { sconf = 0; suna = 0; }
  __syncthreads();
  int conf = 0;
  for (int i = t; i < 16384; i += 256) {
    int b = i >> 11;
    bool sat = false, alla = true;
    #pragma unroll
    for (int l = 0; l < 3; ++l) {
      int f = formula[i * 3 + l];
      int a = assign[b * 512 + (f >> 1)];
      sat = sat || (a == (f & 1));
      alla = alla && (a != 2);
    }
    if (alla && !sat) conf = 1;
  }
  if (conf) atomicOr(&sconf, 1);
  int una = 0;
  for (int i = t; i < 4096; i += 256)
    if (assign[i] == 2) una = 1;
  if (una) atomicOr(&suna, 1);
  __syncthreads();
  if (sconf) {
    if (t < 8) assign[t * 512 + selb[t]] = 2;
  } else if (t == 0 && suna == 0) {
    flags[0] = 1;
  }
}

__global__ __launch_bounds__(256) void k_issat(const float* __restrict__ vsarr,
    const int* __restrict__ assign, const float* __restrict__ wf,
    void* __restrict__ outv, const int* __restrict__ dflag) {
  const int b = blockIdx.x, t = threadIdx.x;
  const int isf32 = dflag[0];
  __shared__ float x[256];
  __shared__ float h[256];
  float s = 0.f;
  for (int v = 0; v < 512; ++v) s += vsarr[((size_t)(b * 512 + v)) * 256 + t];
  x[t] = s / 512.0f;
  __syncthreads();
  const float* wt = wf + WTSP_O;
  float a = 0.f;
  for (int k = 0; k < 256; ++k) a = fmaf(x[k], wt[(size_t)k * 256 + t], a);
  h[t] = gelu_ref(a + wf[W_OFF[20] + t]);
  __syncthreads();
  if (t == 0) {
    const float* w2 = wf + W_OFF[21];
    float l = 0.f;
    for (int k = 0; k < 256; ++k) l = fmaf(h[k], w2[k], l);
    l += wf[W_OFF[22]];
    float sig = 1.f / (1.f + expf(-l));
    if (isf32) ((float*)outv)[b] = sig;
    else ((__hip_bfloat16*)outv)[b] = __float2bfloat16(sig);
  }
  for (int i = t; i < 512; i += 256) {
    float av = (float)assign[b * 512 + i];
    if (isf32) ((float*)outv)[8 + b * 512 + i] = av;
    else ((__hip_bfloat16*)outv)[8 + b * 512 + i] = __float2bfloat16(av);
  }
}

extern "C" void kernel_launch(void* const* d_in, const int* in_sizes, int n_in,
                              void* d_out, int out_size, void* d_ws, size_t ws_size,
                              hipStream_t stream) {
  (void)in_sizes; (void)n_in; (void)out_size; (void)ws_size;
  const int* formula = (const int*)d_in[0];
  float* wf = (float*)d_ws;
  SrcPtrs sp;
  for (int i = 0; i < W_N; ++i) sp.p[i] = d_in[i + 1];
  float* base = wf + BASE_O;
  float* kh   = wf + KH_O;
  float* vh   = wf + VH_O;
  float* qh   = wf + QH_O;
  float* oo   = wf + OO_O;
  float* vs   = wf + VS_O;
  float* sc   = wf + SC_O;
  int* iw     = (int*)(wf + FTOT);
  int* assign = iw;
  int* selb   = iw + 4096;
  int* flags  = iw + 4104;
  int* dflag  = iw + 4107;

  k_detect<<<1, 256, 0, stream>>>((const unsigned short*)d_in[1], dflag);
  k_convert<<<(W_TOT + 255) / 256, 256, 0, stream>>>(sp, wf, dflag);
  k_transpose<<<(T_CUM[T_N] + 255) / 256, 256, 0, stream>>>(wf);
  k_init<<<4096, 256, 0, stream>>>(vs, assign, flags);
  k_base<<<1024, 256, 0, stream>>>(formula, wf, base);
  for (int it = 0; it < 8; ++it) {
    k_clause_kv<<<1024, 256, 0, stream>>>(formula, base, assign, wf, kh, vh, flags);
    k_q<<<256, 256, 0, stream>>>(vs, wf, qh, flags);
    k_attn<<<1024, 256, 0, stream>>>(qh, kh, vh, oo, flags);
    k_outproj<<<256, 256, 0, stream>>>(oo, wf, vs, flags);
    k_scores<<<256, 256, 0, stream>>>(vs, wf, assign, sc, flags);
    k_select<<<8, 256, 0, stream>>>(sc, vs, wf, assign, selb, flags);
    k_conflict_fin<<<1, 256, 0, stream>>>(formula, assign, selb, flags);
  }
  k_issat<<<8, 256, 0, stream>>>(vs, assign, wf, d_out, dflag);
}

// Round 7
// 1033.122 us; speedup vs baseline: 21.0813x; 3.8714x over previous
//
#include <hip/hip_runtime.h>
#include <hip/hip_bf16.h>

#pragma clang fp contract(off)

#define DEVI __device__ __forceinline__

constexpr int Bc = 8, Cc = 2048, Vc = 512, Hc = 256;

constexpr int W_N = 23;
constexpr int W_OFF[W_N] = {
  0,        524288,  655360,  655872,  656384,  656896,  787968,  788224,
  984832,   985600,  1051136, 1051392, 1116928, 1117184, 1117440, 1117444,
  1182980,  1183236, 1183748, 1183752, 1249288, 1249544, 1249800 };
constexpr int W_SZ[W_N] = {
  524288, 131072, 512, 512, 512, 131072, 256, 196608, 768,
  65536, 256, 65536, 256, 256, 1, 65536, 256, 512, 2, 65536, 256, 256, 1 };
constexpr int W_TOT = 1249804;
// slots: 0 lit_emb 1 ce_w1 2 ce_b1 3 ce_g 4 ce_beta 5 ce_w2 6 ce_b2
// 7 attn_in_w 8 attn_in_b 9 attn_out_w 10 attn_out_b 11 vs_w1 12 vs_b1
// 13 vs_w2 14 vs_b2 15 ap_w1 16 ap_b1 17 ap_w2 18 ap_b2 19 sp_w1 20 sp_b1
// 21 sp_w2 22 sp_b2

constexpr size_t WT1_O   = 1249808;            // ce_w1^T   [256k][512r]
constexpr size_t WT2_O   = WT1_O   + 131072;   // ce_w2^T   [512k][256r]
constexpr size_t WTIN_O  = WT2_O   + 131072;   // attn_in^T [256k][768r]
constexpr size_t WTOUT_O = WTIN_O  + 196608;   // attn_out^T[256k][256r]
constexpr size_t WTV1_O  = WTOUT_O + 65536;    // vs_w1^T (unused now)
constexpr size_t WTAP_O  = WTV1_O  + 65536;    // ap_w1^T
constexpr size_t WTSP_O  = WTAP_O  + 65536;    // sp_w1^T
constexpr size_t BASE_O  = WTSP_O  + 65536;    // (16384,256)
constexpr size_t KB_O    = BASE_O  + 4194304;  // base @ Wk^T (no bias)
constexpr size_t VB_O    = KB_O    + 4194304;  // base @ Wv^T (no bias)
constexpr size_t Q8_O    = VB_O    + 4194304;  // (8,256)
constexpr size_t QBK_O   = Q8_O    + 2048;     // (64)  q.bk per bh
constexpr size_t OO8_O   = QBK_O   + 64;       // (8,256)
constexpr size_t VS8_O   = OO8_O   + 2048;     // (8,256)
constexpr size_t FTOT    = VS8_O   + 2048;     // ~58 MB + int area

constexpr int T_N = 7;
constexpr int T_SRC[T_N]  = { 524288, 656896, 788224, 985600, 1051392, 1117444, 1183752 };
constexpr size_t T_DST[T_N] = { WT1_O, WT2_O, WTIN_O, WTOUT_O, WTV1_O, WTAP_O, WTSP_O };
constexpr int T_ROWS[T_N] = { 512, 256, 768, 256, 256, 256, 256 };
constexpr int T_L2C[T_N]  = { 8, 9, 8, 8, 8, 8, 8 };
constexpr int T_CUM[T_N + 1] = { 0, 131072, 262144, 458752, 524288, 589824, 655360, 720896 };

struct SrcPtrs { const void* p[W_N]; };

DEVI float gelu_ref(float x) {
  return (x * (erff(x / 1.41421356237309504880f) + 1.0f)) * 0.5f;
}

__global__ __launch_bounds__(256) void k_detect(const unsigned short* __restrict__ lit,
                                                int* __restrict__ dflag) {
  __shared__ int red[256];
  int t = threadIdx.x, c = 0;
  for (int i = t; i < 4096; i += 256) {
    unsigned e = (lit[i] >> 7) & 0xFF;
    if (e >= 0x8F) c++;
  }
  red[t] = c;
  __syncthreads();
  for (int s = 128; s > 0; s >>= 1) {
    if (t < s) red[t] += red[t + s];
    __syncthreads();
  }
  if (t == 0) dflag[0] = (red[0] > 64) ? 1 : 0;
}

__global__ __launch_bounds__(256) void k_convert(SrcPtrs sp, float* __restrict__ wf,
                                                 const int* __restrict__ dflag) {
  int idx = blockIdx.x * 256 + threadIdx.x;
  if (idx >= W_TOT) return;
  const int isf32 = dflag[0];
  int i = 0;
  while (i + 1 < W_N && idx >= W_OFF[i + 1]) i++;
  int j = idx - W_OFF[i];
  float v = 0.f;
  if (j < W_SZ[i]) {
    if (isf32) v = ((const float*)sp.p[i])[j];
    else {
      unsigned int u = (unsigned int)((const unsigned short*)sp.p[i])[j] << 16;
      v = __uint_as_float(u);
    }
  }
  wf[idx] = v;
}

__global__ __launch_bounds__(256) void k_transpose(float* __restrict__ wf) {
  int idx = blockIdx.x * 256 + threadIdx.x;
  if (idx >= T_CUM[T_N]) return;
  int mi = 0;
  while (mi + 1 < T_N && idx >= T_CUM[mi + 1]) mi++;
  int local = idx - T_CUM[mi];
  int cols = 1 << T_L2C[mi];
  int r = local >> T_L2C[mi];
  int c = local & (cols - 1);
  wf[T_DST[mi] + (size_t)c * T_ROWS[mi] + r] = wf[T_SRC[mi] + (size_t)local];
}

__global__ __launch_bounds__(256) void k_init(float* __restrict__ vs8,
    int* __restrict__ assign, int* __restrict__ flags) {
  int idx = blockIdx.x * 256 + threadIdx.x;   // grid covers 4096
  assign[idx] = 2;
  if (idx < 2048) vs8[idx] = 0.f;
  if (idx < 3) flags[idx] = 0;   // 0: done, 1: any_conf, 2: any_unassigned
}

// ---------------- clause embedding (once) ----------------
__global__ __launch_bounds__(256) void k_base(const int* __restrict__ formula,
    const float* __restrict__ wf, float* __restrict__ base) {
  __shared__ float xs[16][256];
  __shared__ float h1[16][513];
  __shared__ float mv[16], vr[16];
  const int t = threadIdx.x;
  const int n0 = blockIdx.x * 16;
  const float* lit = wf + W_OFF[0];
  for (int r = 0; r < 16; ++r) {
    int n = n0 + r;
    int f0 = formula[n*3+0], f1 = formula[n*3+1], f2 = formula[n*3+2];
    xs[r][t] = (lit[f0*256 + t] + lit[f1*256 + t] + lit[f2*256 + t]) / 3.0f;
  }
  __syncthreads();
  {
    const float* w1t = wf + WT1_O;
    float a0[16], a1[16];
    #pragma unroll
    for (int r = 0; r < 16; ++r) { a0[r] = 0.f; a1[r] = 0.f; }
    for (int k = 0; k < 256; ++k) {
      float wa = w1t[(size_t)k * 512 + t];
      float wb = w1t[(size_t)k * 512 + 256 + t];
      #pragma unroll
      for (int r = 0; r < 16; ++r) {
        a0[r] = fmaf(xs[r][k], wa, a0[r]);
        a1[r] = fmaf(xs[r][k], wb, a1[r]);
      }
    }
    float b0 = wf[W_OFF[2] + t], b1b = wf[W_OFF[2] + t + 256];
    #pragma unroll
    for (int r = 0; r < 16; ++r) {
      h1[r][t] = a0[r] + b0;
      h1[r][t + 256] = a1[r] + b1b;
    }
  }
  __syncthreads();
  if (t < 16) {
    float s = 0.f;
    for (int k = 0; k < 512; ++k) s += h1[t][k];
    float m = s / 512.0f;
    float v = 0.f;
    for (int k = 0; k < 512; ++k) { float d = h1[t][k] - m; float d2 = d * d; v += d2; }
    mv[t] = m; vr[t] = v / 512.0f;
  }
  __syncthreads();
  {
    const float* g  = wf + W_OFF[3];
    const float* be = wf + W_OFF[4];
    for (int r = 0; r < 16; ++r) {
      float sd = sqrtf(vr[r] + 1e-5f);
      for (int c = t; c < 512; c += 256) {
        float val = (h1[r][c] - mv[r]) / sd * g[c] + be[c];
        h1[r][c] = gelu_ref(val);
      }
    }
  }
  __syncthreads();
  {
    const float* w2t = wf + WT2_O;
    float acc[16];
    #pragma unroll
    for (int r = 0; r < 16; ++r) acc[r] = 0.f;
    for (int k = 0; k < 512; ++k) {
      float wk = w2t[(size_t)k * 256 + t];
      #pragma unroll
      for (int r = 0; r < 16; ++r) acc[r] = fmaf(h1[r][k], wk, acc[r]);
    }
    float b2 = wf[W_OFF[6] + t];
    for (int r = 0; r < 16; ++r)
      base[(size_t)(n0 + r) * 256 + t] = acc[r] + b2;
  }
}

// Kb = base @ Wk^T, Vb = base @ Wv^T (no bias, no gating) — once.
__global__ __launch_bounds__(256) void k_kvbase(const float* __restrict__ base,
    const float* __restrict__ wf, float* __restrict__ Kb, float* __restrict__ Vb) {
  __shared__ float xs[16][256];
  const int t = threadIdx.x;
  const int n0 = blockIdx.x * 16;
  for (int r = 0; r < 16; ++r) xs[r][t] = base[(size_t)(n0 + r) * 256 + t];
  __syncthreads();
  const float* wt = wf + WTIN_O;
  float aK[16], aV[16];
  #pragma unroll
  for (int r = 0; r < 16; ++r) { aK[r] = 0.f; aV[r] = 0.f; }
  for (int k = 0; k < 256; ++k) {
    float wa = wt[(size_t)k * 768 + 256 + t];
    float wb = wt[(size_t)k * 768 + 512 + t];
    #pragma unroll
    for (int r = 0; r < 16; ++r) {
      aK[r] = fmaf(xs[r][k], wa, aK[r]);
      aV[r] = fmaf(xs[r][k], wb, aV[r]);
    }
  }
  for (int r = 0; r < 16; ++r) {
    Kb[(size_t)(n0 + r) * 256 + t] = aK[r];
    Vb[(size_t)(n0 + r) * 256 + t] = aV[r];
  }
}

// ---------------- per-iteration ----------------
// q row per batch + q.bk per (b,h)
__global__ __launch_bounds__(256) void k_q8(const float* __restrict__ vs8,
    const float* __restrict__ wf, float* __restrict__ q8, float* __restrict__ qbk,
    const int* __restrict__ flags) {
  if (flags[0]) return;
  const int b = blockIdx.x, t = threadIdx.x;
  __shared__ float xv[256], qs[256];
  xv[t] = vs8[b * 256 + t];
  __syncthreads();
  const float* wt = wf + WTIN_O;
  float acc = 0.f;
  for (int k = 0; k < 256; ++k) acc = fmaf(xv[k], wt[(size_t)k * 768 + t], acc);
  float q = acc + wf[W_OFF[8] + t];
  q8[b * 256 + t] = q;
  qs[t] = q;
  __syncthreads();
  if (t < 8) {
    const float* bk = wf + W_OFF[8] + 256;
    float s = 0.f;
    for (int d = 0; d < 32; ++d) s = fmaf(qs[t * 32 + d], bk[t * 32 + d], s);
    qbk[b * 8 + t] = s;
  }
}

// attention per (b,h): s_j = fac_j*(q.Kb_j) + q.bk ; exact-max softmax;
// O = (sum w_j Vb_j)/L + bv,  w_j = exp(s_j-M)*fac_j
__global__ __launch_bounds__(256) void k_attn8(const int* __restrict__ formula,
    const int* __restrict__ assign, const float* __restrict__ Kb,
    const float* __restrict__ Vb, const float* __restrict__ q8,
    const float* __restrict__ qbk, const float* __restrict__ wf,
    float* __restrict__ oo8, const int* __restrict__ flags) {
  if (flags[0]) return;
  __shared__ float sS[2048];      // s, then w = u*fac
  __shared__ float sF[2048];      // fac
  __shared__ float sRed[256];
  __shared__ float sO[8][32];
  __shared__ float sM, sL;
  const int bh = blockIdx.x, b = bh >> 3, h = bh & 7;
  const int t = threadIdx.x;
  const float FAC1 = 1.0f - 0.9f;   // exact f32 of reference gating factor

  float qreg[32];
  {
    const float* qp = q8 + b * 256 + h * 32;
    #pragma unroll
    for (int d = 0; d < 32; ++d) qreg[d] = qp[d];
  }
  const float qb = qbk[bh];

  // phase A: s_j, fac_j, M
  float mloc = -3.402823466e38f;
  for (int i = 0; i < 8; ++i) {
    int j = i * 256 + t;
    int n = b * 2048 + j;
    bool sat = false;
    #pragma unroll
    for (int l = 0; l < 3; ++l) {
      int f = formula[n * 3 + l];
      int a = assign[b * 512 + (f >> 1)];
      sat = sat || (a == (f & 1));
    }
    float fac = sat ? FAC1 : 1.0f;
    const float* kr = Kb + (size_t)n * 256 + h * 32;
    float p = 0.f;
    #pragma unroll
    for (int d = 0; d < 32; ++d) p = fmaf(qreg[d], kr[d], p);
    float s = fmaf(fac, p, qb);
    sS[j] = s; sF[j] = fac;
    mloc = fmaxf(mloc, s);
  }
  sRed[t] = mloc;
  __syncthreads();
  for (int st = 128; st > 0; st >>= 1) {
    if (t < st) sRed[t] = fmaxf(sRed[t], sRed[t + st]);
    __syncthreads();
  }
  if (t == 0) sM = sRed[0];
  __syncthreads();
  const float M = sM;

  // phase B1: u, L, w
  float lloc = 0.f;
  for (int i = 0; i < 8; ++i) {
    int j = t * 8 + i;              // 8 consecutive j per thread, ascending
    float u = expf(sS[j] - M);
    lloc += u;
    sS[j] = u * sF[j];
  }
  __syncthreads();
  sRed[t] = lloc;
  __syncthreads();
  for (int st = 128; st > 0; st >>= 1) {
    if (t < st) sRed[t] = sRed[t] + sRed[t + st];
    __syncthreads();
  }
  if (t == 0) sL = sRed[0];
  __syncthreads();
  const float L = sL;

  // phase B2: PV, 8 j-groups x 32 d
  {
    const int jg = t >> 5, d = t & 31;
    float acc = 0.f;
    const float* vbase = Vb + ((size_t)(b * 2048 + jg * 256)) * 256 + h * 32 + d;
    for (int jj = 0; jj < 256; ++jj)
      acc = fmaf(sS[jg * 256 + jj], vbase[(size_t)jj * 256], acc);
    sO[jg][d] = acc;
  }
  __syncthreads();
  if (t < 32) {
    float o = sO[0][t];
    #pragma unroll
    for (int g = 1; g < 8; ++g) o += sO[g][t];
    float bv = wf[W_OFF[8] + 512 + h * 32 + t];
    oo8[b * 256 + h * 32 + t] = o / L + bv;
  }
}

// out-proj row, sel = first unassigned, ap MLP -> new_a, per-batch conflict
__global__ __launch_bounds__(256) void k_update(const int* __restrict__ formula,
    const float* __restrict__ oo8, const float* __restrict__ wf,
    float* __restrict__ vs8, int* __restrict__ assign, int* __restrict__ selb,
    int* __restrict__ flags) {
  if (flags[0]) return;
  const int b = blockIdx.x, t = threadIdx.x;
  __shared__ float xv[256], hh[256];
  __shared__ int ssel, sna;
  if (t == 0) ssel = 512;
  // out-proj (vs row)
  {
    __shared__ float xo[256];
    xo[t] = oo8[b * 256 + t];
    __syncthreads();
    const float* wt = wf + WTOUT_O;
    float acc = 0.f;
    for (int k = 0; k < 256; ++k) acc = fmaf(xo[k], wt[(size_t)k * 256 + t], acc);
    float v = acc + wf[W_OFF[10] + t];
    vs8[b * 256 + t] = v;
    xv[t] = v;
  }
  __syncthreads();
  for (int i = t; i < 512; i += 256)
    if (assign[b * 512 + i] == 2) atomicMin(&ssel, i);
  __syncthreads();
  const int sel = (ssel == 512) ? 0 : ssel;
  // ap MLP
  {
    const float* wt = wf + WTAP_O;
    float a = 0.f;
    for (int k = 0; k < 256; ++k) a = fmaf(xv[k], wt[(size_t)k * 256 + t], a);
    hh[t] = gelu_ref(a + wf[W_OFF[16] + t]);
  }
  __syncthreads();
  if (t == 0) {
    const float* w2 = wf + W_OFF[17];
    float l0 = 0.f, l1 = 0.f;
    for (int k = 0; k < 256; ++k) l0 = fmaf(hh[k], w2[k], l0);
    for (int k = 0; k < 256; ++k) l1 = fmaf(hh[k], w2[256 + k], l1);
    l0 += wf[W_OFF[18]];
    l1 += wf[W_OFF[18] + 1];
    int na = (l1 > l0) ? 1 : 0;
    assign[b * 512 + sel] = na;
    selb[b] = sel;
    sna = na;
  }
  __syncthreads();
  const int na = sna;
  // conflict + unassigned for this batch (sel substituted to avoid races)
  int conf = 0, una = 0;
  for (int i = t; i < 2048; i += 256) {
    int n = b * 2048 + i;
    bool sat = false, alla = true;
    #pragma unroll
    for (int l = 0; l < 3; ++l) {
      int f = formula[n * 3 + l];
      int v = f >> 1;
      int a = (v == sel) ? na : assign[b * 512 + v];
      sat = sat || (a == (f & 1));
      alla = alla && (a != 2);
    }
    if (alla && !sat) conf = 1;
  }
  for (int i = t; i < 512; i += 256) {
    int a = (i == sel) ? na : assign[b * 512 + i];
    if (a == 2) una = 1;
  }
  if (conf) atomicOr(&flags[1], 1);
  if (una) atomicOr(&flags[2], 1);
}

__global__ __launch_bounds__(64) void k_fin(int* __restrict__ assign,
    const int* __restrict__ selb, int* __restrict__ flags) {
  if (flags[0]) return;
  const int t = threadIdx.x;
  const int ac = flags[1], ua = flags[2];
  __syncthreads();
  if (ac && t < 8) assign[t * 512 + selb[t]] = 2;
  if (t == 0) {
    if (!ac && !ua) flags[0] = 1;
    flags[1] = 0;
    flags[2] = 0;
  }
}

__global__ __launch_bounds__(256) void k_issat(const float* __restrict__ vs8,
    const int* __restrict__ assign, const float* __restrict__ wf,
    void* __restrict__ outv, const int* __restrict__ dflag) {
  const int b = blockIdx.x, t = threadIdx.x;
  const int isf32 = dflag[0];
  __shared__ float x[256], h[256];
  x[t] = vs8[b * 256 + t];   // mean of 512 identical rows == the row (np pairwise exact)
  __syncthreads();
  const float* wt = wf + WTSP_O;
  float a = 0.f;
  for (int k = 0; k < 256; ++k) a = fmaf(x[k], wt[(size_t)k * 256 + t], a);
  h[t] = gelu_ref(a + wf[W_OFF[20] + t]);
  __syncthreads();
  if (t == 0) {
    const float* w2 = wf + W_OFF[21];
    float l = 0.f;
    for (int k = 0; k < 256; ++k) l = fmaf(h[k], w2[k], l);
    l += wf[W_OFF[22]];
    float sig = 1.f / (1.f + expf(-l));
    if (isf32) ((float*)outv)[b] = sig;
    else ((__hip_bfloat16*)outv)[b] = __float2bfloat16(sig);
  }
  for (int i = t; i < 512; i += 256) {
    float av = (float)assign[b * 512 + i];
    if (isf32) ((float*)outv)[8 + b * 512 + i] = av;
    else ((__hip_bfloat16*)outv)[8 + b * 512 + i] = __float2bfloat16(av);
  }
}

extern "C" void kernel_launch(void* const* d_in, const int* in_sizes, int n_in,
                              void* d_out, int out_size, void* d_ws, size_t ws_size,
                              hipStream_t stream) {
  (void)in_sizes; (void)n_in; (void)out_size; (void)ws_size;
  const int* formula = (const int*)d_in[0];
  float* wf = (float*)d_ws;
  SrcPtrs sp;
  for (int i = 0; i < W_N; ++i) sp.p[i] = d_in[i + 1];
  float* base = wf + BASE_O;
  float* Kb   = wf + KB_O;
  float* Vb   = wf + VB_O;
  float* q8   = wf + Q8_O;
  float* qbk  = wf + QBK_O;
  float* oo8  = wf + OO8_O;
  float* vs8  = wf + VS8_O;
  int* iw     = (int*)(wf + FTOT);
  int* assign = iw;
  int* selb   = iw + 4096;
  int* flags  = iw + 4104;
  int* dflag  = iw + 4107;

  k_detect<<<1, 256, 0, stream>>>((const unsigned short*)d_in[1], dflag);
  k_convert<<<(W_TOT + 255) / 256, 256, 0, stream>>>(sp, wf, dflag);
  k_transpose<<<(T_CUM[T_N] + 255) / 256, 256, 0, stream>>>(wf);
  k_init<<<16, 256, 0, stream>>>(vs8, assign, flags);
  k_base<<<1024, 256, 0, stream>>>(formula, wf, base);
  k_kvbase<<<1024, 256, 0, stream>>>(base, wf, Kb, Vb);
  for (int it = 0; it < 8; ++it) {
    k_q8<<<8, 256, 0, stream>>>(vs8, wf, q8, qbk, flags);
    k_attn8<<<64, 256, 0, stream>>>(formula, assign, Kb, Vb, q8, qbk, wf, oo8, flags);
    k_update<<<8, 256, 0, stream>>>(formula, oo8, wf, vs8, assign, selb, flags);
    k_fin<<<1, 64, 0, stream>>>(assign, selb, flags);
  }
  k_issat<<<8, 256, 0, stream>>>(vs8, assign, wf, d_out, dflag);
}

// Round 8
// 876.330 us; speedup vs baseline: 24.8532x; 1.1789x over previous
//
#include <hip/hip_runtime.h>
#include <hip/hip_bf16.h>

#pragma clang fp contract(off)

#define DEVI __device__ __forceinline__

constexpr int Bc = 8, Cc = 2048, Vc = 512, Hc = 256;

constexpr int W_N = 23;
constexpr int W_OFF[W_N] = {
  0,        524288,  655360,  655872,  656384,  656896,  787968,  788224,
  984832,   985600,  1051136, 1051392, 1116928, 1117184, 1117440, 1117444,
  1182980,  1183236, 1183748, 1183752, 1249288, 1249544, 1249800 };
constexpr int W_SZ[W_N] = {
  524288, 131072, 512, 512, 512, 131072, 256, 196608, 768,
  65536, 256, 65536, 256, 256, 1, 65536, 256, 512, 2, 65536, 256, 256, 1 };
constexpr int W_TOT = 1249804;
// slots: 0 lit_emb 1 ce_w1 2 ce_b1 3 ce_g 4 ce_beta 5 ce_w2 6 ce_b2
// 7 attn_in_w 8 attn_in_b 9 attn_out_w 10 attn_out_b 11 vs_w1 12 vs_b1
// 13 vs_w2 14 vs_b2 15 ap_w1 16 ap_b1 17 ap_w2 18 ap_b2 19 sp_w1 20 sp_b1
// 21 sp_w2 22 sp_b2

constexpr size_t WT1_O   = 1249808;            // ce_w1^T   [256k][512r]
constexpr size_t WT2_O   = WT1_O   + 131072;   // ce_w2^T   [512k][256r]
constexpr size_t WTIN_O  = WT2_O   + 131072;   // attn_in^T [256k][768r]
constexpr size_t WTOUT_O = WTIN_O  + 196608;   // attn_out^T[256k][256r]
constexpr size_t WTV1_O  = WTOUT_O + 65536;    // vs_w1^T (unused)
constexpr size_t WTAP_O  = WTV1_O  + 65536;    // ap_w1^T
constexpr size_t WTSP_O  = WTAP_O  + 65536;    // sp_w1^T
constexpr size_t WCK_O   = WTSP_O  + 65536;    // (Wk·ce_w2)^T [512k][256o]
constexpr size_t WCV_O   = WCK_O   + 131072;   // (Wv·ce_w2)^T
constexpr size_t BCK_O   = WCV_O   + 131072;   // Wk·ce_b2 (256)
constexpr size_t BCV_O   = BCK_O   + 256;      // Wv·ce_b2 (256)
constexpr size_t KB_O    = BCV_O   + 256;      // head-major [b*8+h][2048][32]
constexpr size_t VB_O    = KB_O    + 4194304;
constexpr size_t OO8_O   = VB_O    + 4194304;  // (8,256)
constexpr size_t VS8_O   = OO8_O   + 2048;     // (8,256)
constexpr size_t FTOT    = VS8_O   + 2048;     // ~42 MB + int area

constexpr int T_N = 7;
constexpr int T_SRC[T_N]  = { 524288, 656896, 788224, 985600, 1051392, 1117444, 1183752 };
constexpr size_t T_DST[T_N] = { WT1_O, WT2_O, WTIN_O, WTOUT_O, WTV1_O, WTAP_O, WTSP_O };
constexpr int T_ROWS[T_N] = { 512, 256, 768, 256, 256, 256, 256 };
constexpr int T_L2C[T_N]  = { 8, 9, 8, 8, 8, 8, 8 };
constexpr int T_CUM[T_N + 1] = { 0, 131072, 262144, 458752, 524288, 589824, 655360, 720896 };

struct SrcPtrs { const void* p[W_N]; };

DEVI float gelu_ref(float x) {
  return (x * (erff(x / 1.41421356237309504880f) + 1.0f)) * 0.5f;
}

__global__ __launch_bounds__(256) void k_detect(const unsigned short* __restrict__ lit,
                                                int* __restrict__ dflag) {
  __shared__ int red[256];
  int t = threadIdx.x, c = 0;
  for (int i = t; i < 4096; i += 256) {
    unsigned e = (lit[i] >> 7) & 0xFF;
    if (e >= 0x8F) c++;
  }
  red[t] = c;
  __syncthreads();
  for (int s = 128; s > 0; s >>= 1) {
    if (t < s) red[t] += red[t + s];
    __syncthreads();
  }
  if (t == 0) dflag[0] = (red[0] > 64) ? 1 : 0;
}

__global__ __launch_bounds__(256) void k_convert(SrcPtrs sp, float* __restrict__ wf,
                                                 const int* __restrict__ dflag) {
  int idx = blockIdx.x * 256 + threadIdx.x;
  if (idx >= W_TOT) return;
  const int isf32 = dflag[0];
  int i = 0;
  while (i + 1 < W_N && idx >= W_OFF[i + 1]) i++;
  int j = idx - W_OFF[i];
  float v = 0.f;
  if (j < W_SZ[i]) {
    if (isf32) v = ((const float*)sp.p[i])[j];
    else {
      unsigned int u = (unsigned int)((const unsigned short*)sp.p[i])[j] << 16;
      v = __uint_as_float(u);
    }
  }
  wf[idx] = v;
}

__global__ __launch_bounds__(256) void k_transpose(float* __restrict__ wf) {
  int idx = blockIdx.x * 256 + threadIdx.x;
  if (idx >= T_CUM[T_N]) return;
  int mi = 0;
  while (mi + 1 < T_N && idx >= T_CUM[mi + 1]) mi++;
  int local = idx - T_CUM[mi];
  int cols = 1 << T_L2C[mi];
  int r = local >> T_L2C[mi];
  int c = local & (cols - 1);
  wf[T_DST[mi] + (size_t)c * T_ROWS[mi] + r] = wf[T_SRC[mi] + (size_t)local];
}

// Wck[k][o] = sum_m ce_w2^T[k][m] * Wk[o][m];  bck[o] = sum_m ce_b2[m] * Wk[o][m]
__global__ __launch_bounds__(256) void k_combine(float* __restrict__ wf) {
  const int blk = blockIdx.x, t = threadIdx.x;
  const float* wtin = wf + WTIN_O;
  if (blk < 512) {
    __shared__ float w2row[256];
    w2row[t] = wf[WT2_O + (size_t)blk * 256 + t];
    __syncthreads();
    float aK = 0.f, aV = 0.f;
    for (int m = 0; m < 256; ++m) {
      float w2 = w2row[m];
      aK = fmaf(w2, wtin[(size_t)m * 768 + 256 + t], aK);
      aV = fmaf(w2, wtin[(size_t)m * 768 + 512 + t], aV);
    }
    wf[WCK_O + (size_t)blk * 256 + t] = aK;
    wf[WCV_O + (size_t)blk * 256 + t] = aV;
  } else {
    float aK = 0.f, aV = 0.f;
    for (int m = 0; m < 256; ++m) {
      float b2 = wf[W_OFF[6] + m];
      aK = fmaf(b2, wtin[(size_t)m * 768 + 256 + t], aK);
      aV = fmaf(b2, wtin[(size_t)m * 768 + 512 + t], aV);
    }
    wf[BCK_O + t] = aK;
    wf[BCV_O + t] = aV;
  }
}

__global__ __launch_bounds__(256) void k_init(float* __restrict__ vs8,
    int* __restrict__ assign, int* __restrict__ flags) {
  int idx = blockIdx.x * 256 + threadIdx.x;   // grid covers 4096
  assign[idx] = 2;
  if (idx < 2048) vs8[idx] = 0.f;
  if (idx < 3) flags[idx] = 0;   // 0: done, 1: any_conf, 2: any_unassigned
}

// ---------------- fused clause embedding + K/V projection (once) ----------------
__global__ __launch_bounds__(256) void k_base(const int* __restrict__ formula,
    const float* __restrict__ wf, float* __restrict__ Kb, float* __restrict__ Vb) {
  __shared__ __align__(16) float xs[16][256];
  __shared__ __align__(16) float h1[16][516];
  __shared__ float mv[16], vr[16];
  const int t = threadIdx.x;
  const int n0 = blockIdx.x * 16;
  const float* lit = wf + W_OFF[0];
  for (int r = 0; r < 16; ++r) {
    int n = n0 + r;
    int f0 = formula[n*3+0], f1 = formula[n*3+1], f2 = formula[n*3+2];
    xs[r][t] = (lit[f0*256 + t] + lit[f1*256 + t] + lit[f2*256 + t]) / 3.0f;
  }
  __syncthreads();
  // GEMM1: h1 = x @ ce_w1^T + b1 (cols t, t+256); k-ascending chains, x via float4
  {
    const float* w1t = wf + WT1_O;
    float a0[16], a1[16];
    #pragma unroll
    for (int r = 0; r < 16; ++r) { a0[r] = 0.f; a1[r] = 0.f; }
    for (int k = 0; k < 256; k += 4) {
      float wa0 = w1t[(size_t)(k+0)*512 + t], wa1 = w1t[(size_t)(k+1)*512 + t];
      float wa2 = w1t[(size_t)(k+2)*512 + t], wa3 = w1t[(size_t)(k+3)*512 + t];
      float wb0 = w1t[(size_t)(k+0)*512 + 256 + t], wb1 = w1t[(size_t)(k+1)*512 + 256 + t];
      float wb2 = w1t[(size_t)(k+2)*512 + 256 + t], wb3 = w1t[(size_t)(k+3)*512 + 256 + t];
      #pragma unroll
      for (int r = 0; r < 16; ++r) {
        float4 x4 = *(const float4*)&xs[r][k];
        a0[r] = fmaf(x4.x, wa0, a0[r]);
        a0[r] = fmaf(x4.y, wa1, a0[r]);
        a0[r] = fmaf(x4.z, wa2, a0[r]);
        a0[r] = fmaf(x4.w, wa3, a0[r]);
        a1[r] = fmaf(x4.x, wb0, a1[r]);
        a1[r] = fmaf(x4.y, wb1, a1[r]);
        a1[r] = fmaf(x4.z, wb2, a1[r]);
        a1[r] = fmaf(x4.w, wb3, a1[r]);
      }
    }
    float b0 = wf[W_OFF[2] + t], b1b = wf[W_OFF[2] + t + 256];
    #pragma unroll
    for (int r = 0; r < 16; ++r) {
      h1[r][t] = a0[r] + b0;
      h1[r][t + 256] = a1[r] + b1b;
    }
  }
  __syncthreads();
  // LayerNorm stats: unchanged serial order
  if (t < 16) {
    float s = 0.f;
    for (int k = 0; k < 512; ++k) s += h1[t][k];
    float m = s / 512.0f;
    float v = 0.f;
    for (int k = 0; k < 512; ++k) { float d = h1[t][k] - m; float d2 = d * d; v += d2; }
    mv[t] = m; vr[t] = v / 512.0f;
  }
  __syncthreads();
  {
    const float* g  = wf + W_OFF[3];
    const float* be = wf + W_OFF[4];
    for (int r = 0; r < 16; ++r) {
      float sd = sqrtf(vr[r] + 1e-5f);
      for (int c = t; c < 512; c += 256) {
        float val = (h1[r][c] - mv[r]) / sd * g[c] + be[c];
        h1[r][c] = gelu_ref(val);
      }
    }
  }
  __syncthreads();
  // GEMM2: Kb/Vb col t = g @ Wck^T + bck (k-ascending chains, g via float4)
  {
    const float* wck = wf + WCK_O;
    const float* wcv = wf + WCV_O;
    float aK[16], aV[16];
    #pragma unroll
    for (int r = 0; r < 16; ++r) { aK[r] = 0.f; aV[r] = 0.f; }
    for (int k = 0; k < 512; k += 4) {
      float ck0 = wck[(size_t)(k+0)*256 + t], ck1 = wck[(size_t)(k+1)*256 + t];
      float ck2 = wck[(size_t)(k+2)*256 + t], ck3 = wck[(size_t)(k+3)*256 + t];
      float cv0 = wcv[(size_t)(k+0)*256 + t], cv1 = wcv[(size_t)(k+1)*256 + t];
      float cv2 = wcv[(size_t)(k+2)*256 + t], cv3 = wcv[(size_t)(k+3)*256 + t];
      #pragma unroll
      for (int r = 0; r < 16; ++r) {
        float4 x4 = *(const float4*)&h1[r][k];
        aK[r] = fmaf(x4.x, ck0, aK[r]);
        aK[r] = fmaf(x4.y, ck1, aK[r]);
        aK[r] = fmaf(x4.z, ck2, aK[r]);
        aK[r] = fmaf(x4.w, ck3, aK[r]);
        aV[r] = fmaf(x4.x, cv0, aV[r]);
        aV[r] = fmaf(x4.y, cv1, aV[r]);
        aV[r] = fmaf(x4.z, cv2, aV[r]);
        aV[r] = fmaf(x4.w, cv3, aV[r]);
      }
    }
    float bck = wf[BCK_O + t], bcv = wf[BCV_O + t];
    const int h = t >> 5, d = t & 31;
    for (int r = 0; r < 16; ++r) {
      int n = n0 + r;
      int b = n >> 11, j = n & 2047;
      size_t off = ((size_t)(b * 8 + h) * 2048 + j) * 32 + d;
      Kb[off] = aK[r] + bck;
      Vb[off] = aV[r] + bcv;
    }
  }
}

// ---------------- per-iteration ----------------
// attention per (b,h), with fused q-projection:
// q = vs8[b] @ Wq^T + bq (cols h*32..+32); s_j = fac_j*(q.Kb_j) + q.bk;
// exact-max softmax; O = (sum u_j*fac_j*Vb_j)/L + bv
__global__ __launch_bounds__(256) void k_attn8(const int* __restrict__ formula,
    const int* __restrict__ assign, const float* __restrict__ Kb,
    const float* __restrict__ Vb, const float* __restrict__ wf,
    const float* __restrict__ vs8, float* __restrict__ oo8,
    const int* __restrict__ flags) {
  if (flags[0]) return;
  __shared__ float xv[256], qs[32];
  __shared__ float sS[2048];      // s, then w = u*fac
  __shared__ float sF[2048];      // fac
  __shared__ float sRed[256];
  __shared__ float sO[8][32];
  __shared__ float sM, sL, sQB;
  const int bh = blockIdx.x, b = bh >> 3, h = bh & 7;
  const int t = threadIdx.x;
  const float FAC1 = 1.0f - 0.9f;

  xv[t] = vs8[b * 256 + t];
  __syncthreads();
  if (t < 32) {   // q col h*32+t, sequential k-ascending chain
    const float* wt = wf + WTIN_O;
    const int c = h * 32 + t;
    float acc = 0.f;
    for (int k = 0; k < 256; ++k) acc = fmaf(xv[k], wt[(size_t)k * 768 + c], acc);
    qs[t] = acc + wf[W_OFF[8] + c];
  }
  __syncthreads();
  if (t == 0) {   // q.bk, d-ascending chain
    const float* bk = wf + W_OFF[8] + 256;
    float s = 0.f;
    for (int d = 0; d < 32; ++d) s = fmaf(qs[d], bk[h * 32 + d], s);
    sQB = s;
  }
  __syncthreads();
  float qreg[32];
  #pragma unroll
  for (int d = 0; d < 32; ++d) qreg[d] = qs[d];
  const float qb = sQB;
  const float* kbh = Kb + (size_t)bh * 2048 * 32;
  const float* vbh = Vb + (size_t)bh * 2048 * 32;

  // phase A: s_j, fac_j, M
  float mloc = -3.402823466e38f;
  for (int i = 0; i < 8; ++i) {
    int j = i * 256 + t;
    int n = b * 2048 + j;
    bool sat = false;
    #pragma unroll
    for (int l = 0; l < 3; ++l) {
      int f = formula[n * 3 + l];
      int a = assign[b * 512 + (f >> 1)];
      sat = sat || (a == (f & 1));
    }
    float fac = sat ? FAC1 : 1.0f;
    const float4* kr4 = (const float4*)(kbh + (size_t)j * 32);
    float p = 0.f;
    #pragma unroll
    for (int g = 0; g < 8; ++g) {
      float4 kk = kr4[g];
      p = fmaf(qreg[4*g+0], kk.x, p);
      p = fmaf(qreg[4*g+1], kk.y, p);
      p = fmaf(qreg[4*g+2], kk.z, p);
      p = fmaf(qreg[4*g+3], kk.w, p);
    }
    float s = fmaf(fac, p, qb);
    sS[j] = s; sF[j] = fac;
    mloc = fmaxf(mloc, s);
  }
  sRed[t] = mloc;
  __syncthreads();
  for (int st = 128; st > 0; st >>= 1) {
    if (t < st) sRed[t] = fmaxf(sRed[t], sRed[t + st]);
    __syncthreads();
  }
  if (t == 0) sM = sRed[0];
  __syncthreads();
  const float M = sM;

  // phase B1: u, L, w
  float lloc = 0.f;
  for (int i = 0; i < 8; ++i) {
    int j = t * 8 + i;
    float u = expf(sS[j] - M);
    lloc += u;
    sS[j] = u * sF[j];
  }
  __syncthreads();
  sRed[t] = lloc;
  __syncthreads();
  for (int st = 128; st > 0; st >>= 1) {
    if (t < st) sRed[t] = sRed[t] + sRed[t + st];
    __syncthreads();
  }
  if (t == 0) sL = sRed[0];
  __syncthreads();
  const float L = sL;

  // phase B2: PV, 8 j-groups x 32 d (head-major Vb, coalesced)
  {
    const int jg = t >> 5, d = t & 31;
    float acc = 0.f;
    const float* vbase = vbh + (size_t)(jg * 256) * 32 + d;
    for (int jj = 0; jj < 256; ++jj)
      acc = fmaf(sS[jg * 256 + jj], vbase[(size_t)jj * 32], acc);
    sO[jg][d] = acc;
  }
  __syncthreads();
  if (t < 32) {
    float o = sO[0][t];
    #pragma unroll
    for (int g = 1; g < 8; ++g) o += sO[g][t];
    float bv = wf[W_OFF[8] + 512 + h * 32 + t];
    oo8[b * 256 + h * 32 + t] = o / L + bv;
  }
}

// out-proj row, sel = first unassigned, ap MLP -> new_a, per-batch conflict
__global__ __launch_bounds__(256) void k_update(const int* __restrict__ formula,
    const float* __restrict__ oo8, const float* __restrict__ wf,
    float* __restrict__ vs8, int* __restrict__ assign, int* __restrict__ selb,
    int* __restrict__ flags) {
  if (flags[0]) return;
  const int b = blockIdx.x, t = threadIdx.x;
  __shared__ float xv[256], hh[256];
  __shared__ int ssel, sna;
  if (t == 0) ssel = 512;
  {
    __shared__ float xo[256];
    xo[t] = oo8[b * 256 + t];
    __syncthreads();
    const float* wt = wf + WTOUT_O;
    float acc = 0.f;
    for (int k = 0; k < 256; ++k) acc = fmaf(xo[k], wt[(size_t)k * 256 + t], acc);
    float v = acc + wf[W_OFF[10] + t];
    vs8[b * 256 + t] = v;
    xv[t] = v;
  }
  __syncthreads();
  for (int i = t; i < 512; i += 256)
    if (assign[b * 512 + i] == 2) atomicMin(&ssel, i);
  __syncthreads();
  const int sel = (ssel == 512) ? 0 : ssel;
  {
    const float* wt = wf + WTAP_O;
    float a = 0.f;
    for (int k = 0; k < 256; ++k) a = fmaf(xv[k], wt[(size_t)k * 256 + t], a);
    hh[t] = gelu_ref(a + wf[W_OFF[16] + t]);
  }
  __syncthreads();
  if (t == 0) {
    const float* w2 = wf + W_OFF[17];
    float l0 = 0.f, l1 = 0.f;
    for (int k = 0; k < 256; ++k) l0 = fmaf(hh[k], w2[k], l0);
    for (int k = 0; k < 256; ++k) l1 = fmaf(hh[k], w2[256 + k], l1);
    l0 += wf[W_OFF[18]];
    l1 += wf[W_OFF[18] + 1];
    int na = (l1 > l0) ? 1 : 0;
    assign[b * 512 + sel] = na;
    selb[b] = sel;
    sna = na;
  }
  __syncthreads();
  const int na = sna;
  int conf = 0, una = 0;
  for (int i = t; i < 2048; i += 256) {
    int n = b * 2048 + i;
    bool sat = false, alla = true;
    #pragma unroll
    for (int l = 0; l < 3; ++l) {
      int f = formula[n * 3 + l];
      int v = f >> 1;
      int a = (v == sel) ? na : assign[b * 512 + v];
      sat = sat || (a == (f & 1));
      alla = alla && (a != 2);
    }
    if (alla && !sat) conf = 1;
  }
  for (int i = t; i < 512; i += 256) {
    int a = (i == sel) ? na : assign[b * 512 + i];
    if (a == 2) una = 1;
  }
  if (conf) atomicOr(&flags[1], 1);
  if (una) atomicOr(&flags[2], 1);
}

__global__ __launch_bounds__(64) void k_fin(int* __restrict__ assign,
    const int* __restrict__ selb, int* __restrict__ flags) {
  if (flags[0]) return;
  const int t = threadIdx.x;
  const int ac = flags[1], ua = flags[2];
  __syncthreads();
  if (ac && t < 8) assign[t * 512 + selb[t]] = 2;
  if (t == 0) {
    if (!ac && !ua) flags[0] = 1;
    flags[1] = 0;
    flags[2] = 0;
  }
}

__global__ __launch_bounds__(256) void k_issat(const float* __restrict__ vs8,
    const int* __restrict__ assign, const float* __restrict__ wf,
    void* __restrict__ outv, const int* __restrict__ dflag) {
  const int b = blockIdx.x, t = threadIdx.x;
  const int isf32 = dflag[0];
  __shared__ float x[256], h[256];
  x[t] = vs8[b * 256 + t];   // mean of 512 identical rows == the row
  __syncthreads();
  const float* wt = wf + WTSP_O;
  float a = 0.f;
  for (int k = 0; k < 256; ++k) a = fmaf(x[k], wt[(size_t)k * 256 + t], a);
  h[t] = gelu_ref(a + wf[W_OFF[20] + t]);
  __syncthreads();
  if (t == 0) {
    const float* w2 = wf + W_OFF[21];
    float l = 0.f;
    for (int k = 0; k < 256; ++k) l = fmaf(h[k], w2[k], l);
    l += wf[W_OFF[22]];
    float sig = 1.f / (1.f + expf(-l));
    if (isf32) ((float*)outv)[b] = sig;
    else ((__hip_bfloat16*)outv)[b] = __float2bfloat16(sig);
  }
  for (int i = t; i < 512; i += 256) {
    float av = (float)assign[b * 512 + i];
    if (isf32) ((float*)outv)[8 + b * 512 + i] = av;
    else ((__hip_bfloat16*)outv)[8 + b * 512 + i] = __float2bfloat16(av);
  }
}

extern "C" void kernel_launch(void* const* d_in, const int* in_sizes, int n_in,
                              void* d_out, int out_size, void* d_ws, size_t ws_size,
                              hipStream_t stream) {
  (void)in_sizes; (void)n_in; (void)out_size; (void)ws_size;
  const int* formula = (const int*)d_in[0];
  float* wf = (float*)d_ws;
  SrcPtrs sp;
  for (int i = 0; i < W_N; ++i) sp.p[i] = d_in[i + 1];
  float* Kb   = wf + KB_O;
  float* Vb   = wf + VB_O;
  float* oo8  = wf + OO8_O;
  float* vs8  = wf + VS8_O;
  int* iw     = (int*)(wf + FTOT);
  int* assign = iw;
  int* selb   = iw + 4096;
  int* flags  = iw + 4104;
  int* dflag  = iw + 4107;

  k_detect<<<1, 256, 0, stream>>>((const unsigned short*)d_in[1], dflag);
  k_convert<<<(W_TOT + 255) / 256, 256, 0, stream>>>(sp, wf, dflag);
  k_transpose<<<(T_CUM[T_N] + 255) / 256, 256, 0, stream>>>(wf);
  k_combine<<<513, 256, 0, stream>>>(wf);
  k_init<<<16, 256, 0, stream>>>(vs8, assign, flags);
  k_base<<<1024, 256, 0, stream>>>(formula, wf, Kb, Vb);
  for (int it = 0; it < 8; ++it) {
    k_attn8<<<64, 256, 0, stream>>>(formula, assign, Kb, Vb, wf, vs8, oo8, flags);
    k_update<<<8, 256, 0, stream>>>(formula, oo8, wf, vs8, assign, selb, flags);
    k_fin<<<1, 64, 0, stream>>>(assign, selb, flags);
  }
  k_issat<<<8, 256, 0, stream>>>(vs8, assign, wf, d_out, dflag);
}